// Round 2
// baseline (7684.145 us; speedup 1.0000x reference)
//
#include <hip/hip_runtime.h>
#include <hip/hip_bf16.h>

// BiMamba: bidirectional Mamba2 forward, MI355X/gfx950.
// Per direction: in-proj (bf16 MFMA GEMM, split z / xBC outputs, A-row flip for
// backward) -> exact fp32 dt/dA -> depthwise causal conv+silu -> sequential SSM
// scan (fp32 state) -> gated RMSNorm (in-place) -> combined out-proj+fusion GEMM
// accumulating fp32 into d_out (combined weight = fus_half @ out_w, precomputed
// per direction by a small GEMM).
// Workspace budget ~199 MB (round-1 crash attributed to ws overflow at 378 MB).

#define BATCHN 4
#define SEQL 4096
#define DMODEL 768
#define DINNER 1536
#define DSTATE 64
#define HN 24
#define CONVDIM 1664          // DINNER + 2*DSTATE
#define NROWS_XBC 3200        // DINNER + CONVDIM  (in_w rows we GEMM; dt rows excluded)
#define NTOK (BATCHN*SEQL)    // 16384

typedef short v8s __attribute__((ext_vector_type(8)));
typedef float v4f __attribute__((ext_vector_type(4)));
typedef __hip_bfloat16 bf16;

__device__ __forceinline__ int flip_row(int r) {
  return (r & ~4095) | (4095 - (r & 4095));
}

// ---------------- cast kernels ----------------

__global__ void cast_x_kernel(const float* __restrict__ x, bf16* __restrict__ xf) {
  int idx = blockIdx.x * 256 + threadIdx.x;
  xf[idx] = __float2bfloat16(x[idx]);
}

// plain fp32->bf16 cast of a packed region (grid covers exactly)
__global__ void cast_kernel(const float* __restrict__ src, bf16* __restrict__ dst) {
  int idx = blockIdx.x * 256 + threadIdx.x;
  dst[idx] = __float2bfloat16(src[idx]);
}

// strided cast: dst[j*cols+m] = src[j*src_stride+m]  (extract fus_w half)
__global__ void cast_strided_kernel(const float* __restrict__ src, bf16* __restrict__ dst,
                                    int cols, int src_stride) {
  int idx = blockIdx.x * 256 + threadIdx.x;
  int j = idx / cols, m = idx % cols;
  dst[idx] = __float2bfloat16(src[(size_t)j * src_stride + m]);
}

// transpose cast: dst[k*768+c] = src[c*1536+k], k<1536, c<768 (out_w -> owT)
__global__ void transpose_ow_kernel(const float* __restrict__ src, bf16* __restrict__ dst) {
  int idx = blockIdx.x * 256 + threadIdx.x;
  int k = idx / DMODEL, c = idx % DMODEL;
  dst[idx] = __float2bfloat16(src[(size_t)c * DINNER + k]);
}

// ---------------- bf16 MFMA GEMM: C[M,N] = A[M,K] @ B[N,K]^T ----------------
// Block 256 = 4 waves (2x2) -> 128x128 tile; wave = 64x64 = 4x4 MFMA 16x16x32.
// flip_a: read A rows seq-reversed. flip_c: write C rows seq-reversed.
// accum: C += result (fp32 out only). bias: per-col fp32 bias.
template <bool OUT_BF16>
__global__ __launch_bounds__(256) void gemm_bt(
    const bf16* __restrict__ A, const bf16* __restrict__ B, void* __restrict__ C,
    int K, int ldc, int flip_a, int flip_c, int accum, const float* __restrict__ bias) {
  int tid = threadIdx.x;
  int wave = tid >> 6, lane = tid & 63;
  int l15 = lane & 15, quad = lane >> 4;
  int m0 = blockIdx.x * 128 + (wave >> 1) * 64;
  int n0 = blockIdx.y * 128 + (wave & 1) * 64;
  const short* Ap = (const short*)A;
  const short* Bp = (const short*)B;
  v4f acc[4][4];
#pragma unroll
  for (int i = 0; i < 4; i++)
#pragma unroll
    for (int j = 0; j < 4; j++) acc[i][j] = {0.f, 0.f, 0.f, 0.f};

  int arow[4];
#pragma unroll
  for (int i = 0; i < 4; i++) {
    int r = m0 + i * 16 + l15;
    arow[i] = flip_a ? flip_row(r) : r;
  }

  for (int k0 = 0; k0 < K; k0 += 32) {
    v8s af[4], bfr[4];
#pragma unroll
    for (int i = 0; i < 4; i++) {
      af[i]  = *(const v8s*)(Ap + (size_t)arow[i] * K + k0 + quad * 8);
      bfr[i] = *(const v8s*)(Bp + (size_t)(n0 + i * 16 + l15) * K + k0 + quad * 8);
    }
#pragma unroll
    for (int i = 0; i < 4; i++)
#pragma unroll
      for (int j = 0; j < 4; j++)
        acc[i][j] = __builtin_amdgcn_mfma_f32_16x16x32_bf16(af[i], bfr[j], acc[i][j], 0, 0, 0);
  }

  float bv[4];
#pragma unroll
  for (int j = 0; j < 4; j++) bv[j] = bias ? bias[n0 + j * 16 + l15] : 0.f;

#pragma unroll
  for (int i = 0; i < 4; i++) {
#pragma unroll
    for (int r = 0; r < 4; r++) {
      int row = m0 + i * 16 + quad * 4 + r;
      int orow = flip_c ? flip_row(row) : row;
#pragma unroll
      for (int j = 0; j < 4; j++) {
        int col = n0 + j * 16 + l15;
        float v = acc[i][j][r] + bv[j];
        size_t off = (size_t)orow * ldc + col;
        if (OUT_BF16) {
          ((bf16*)C)[off] = __float2bfloat16(v);
        } else {
          float* Cf = (float*)C;
          if (accum) v += Cf[off];
          Cf[off] = v;
        }
      }
    }
  }
}

// ---------------- fp32 dt path ----------------
// Block per token: stage x row in LDS, 4 waves x 6 heads of exact fp32 dots,
// then softplus and dA = exp(-dt * exp(A_log)). Weights stay hot in L1/L2.
__global__ __launch_bounds__(256) void dt_kernel(
    const float* __restrict__ x, const float* __restrict__ in_w,
    const float* __restrict__ dt_bias, const float* __restrict__ A_log,
    float* __restrict__ dt_o, float* __restrict__ dA_o, int flip) {
  int token = blockIdx.x;
  int srow = flip ? flip_row(token) : token;
  __shared__ float sx[DMODEL];
  const float* xp = x + (size_t)srow * DMODEL;
  for (int i = threadIdx.x; i < DMODEL; i += 256) sx[i] = xp[i];
  __syncthreads();
  int w = threadIdx.x >> 6, lane = threadIdx.x & 63;
#pragma unroll
  for (int hh = 0; hh < 6; hh++) {
    int h = w * 6 + hh;
    const float* wp = in_w + (size_t)(NROWS_XBC + h) * DMODEL;
    float s = 0.f;
#pragma unroll
    for (int i = 0; i < 12; i++) {
      int k = lane + i * 64;
      s += sx[k] * wp[k];
    }
    for (int off = 32; off > 0; off >>= 1) s += __shfl_down(s, off);
    if (lane == 0) {
      float v = s + dt_bias[h];
      float dt = (v > 20.f) ? v : log1pf(expf(v));
      float dA = expf(-dt * expf(A_log[h]));
      dt_o[(size_t)token * HN + h] = dt;
      dA_o[(size_t)token * HN + h] = dA;
    }
  }
}

// ---------------- depthwise causal conv (width 4) + silu ----------------
__global__ void conv_kernel(const bf16* __restrict__ src, const float* __restrict__ cw,
                            const float* __restrict__ cb, bf16* __restrict__ out) {
  int idx = blockIdx.x * 256 + threadIdx.x;  // covers NTOK*CONVDIM exactly
  int token = idx / CONVDIM, c = idx % CONVDIM;
  int b = token >> 12, l = token & 4095;
  float acc = cb[c];
#pragma unroll
  for (int j = 0; j < 4; j++) {
    int ls = l - 3 + j;
    if (ls >= 0)
      acc += __bfloat162float(src[(size_t)((b << 12) | ls) * CONVDIM + c]) * cw[c * 4 + j];
  }
  float s = acc / (1.f + expf(-acc));
  out[(size_t)token * CONVDIM + c] = __float2bfloat16(s);
}

// ---------------- sequential SSM scan ----------------
// One block per (b,h). lane=p (64 = HEADDIM), wave w owns n in [16w,16w+16).
// fp32 state in registers; LDS double-buffered staging with global prefetch;
// one barrier per step; cross-wave y reduction via LDS.
__global__ __launch_bounds__(256) void scan_kernel(
    const bf16* __restrict__ xbc, const float* __restrict__ dtb,
    const float* __restrict__ dab, const float* __restrict__ Dp,
    bf16* __restrict__ y) {
  int b = blockIdx.x / HN, h = blockIdx.x % HN;
  int tid = threadIdx.x, w = tid >> 6, lane = tid & 63;
  __shared__ __align__(16) float s_x[2][64];
  __shared__ __align__(16) float s_B[2][64];
  __shared__ __align__(16) float s_C[2][64];
  __shared__ float s_scal[2][2];
  __shared__ float s_part[2][4][64];
  float hs[16];
#pragma unroll
  for (int i = 0; i < 16; i++) hs[i] = 0.f;
  const size_t tok0 = (size_t)b * SEQL;
  float Dh = Dp[h];

  {  // stage t=0
    size_t rb = tok0 * CONVDIM;
    float v = 0.f;
    if (tid < 64) v = __bfloat162float(xbc[rb + h * 64 + tid]);
    else if (tid < 128) v = __bfloat162float(xbc[rb + 1536 + (tid - 64)]);
    else if (tid < 192) v = __bfloat162float(xbc[rb + 1600 + (tid - 128)]);
    else if (tid == 192) v = dtb[tok0 * HN + h];
    else if (tid == 193) v = dab[tok0 * HN + h];
    if (tid < 64) s_x[0][tid] = v;
    else if (tid < 128) s_B[0][tid - 64] = v;
    else if (tid < 192) s_C[0][tid - 128] = v;
    else if (tid == 192) s_scal[0][0] = v;
    else if (tid == 193) s_scal[0][1] = v;
  }
  __syncthreads();

  for (int t = 0; t < SEQL; t++) {
    int cur = t & 1, nxt = cur ^ 1;
    float pre = 0.f;
    if (t + 1 < SEQL) {  // prefetch next step (global loads issue early)
      size_t rb = (tok0 + t + 1) * CONVDIM;
      if (tid < 64) pre = __bfloat162float(xbc[rb + h * 64 + tid]);
      else if (tid < 128) pre = __bfloat162float(xbc[rb + 1536 + (tid - 64)]);
      else if (tid < 192) pre = __bfloat162float(xbc[rb + 1600 + (tid - 128)]);
      else if (tid == 192) pre = dtb[(tok0 + t + 1) * HN + h];
      else if (tid == 193) pre = dab[(tok0 + t + 1) * HN + h];
    }
    float dtv = s_scal[cur][0], dAv = s_scal[cur][1];
    float xv = s_x[cur][lane];
    float dtx = dtv * xv;
    float Br[16], Cr[16];
    const float4* Bq = (const float4*)&s_B[cur][w * 16];
    const float4* Cq = (const float4*)&s_C[cur][w * 16];
#pragma unroll
    for (int q = 0; q < 4; q++) {
      *(float4*)&Br[q * 4] = Bq[q];
      *(float4*)&Cr[q * 4] = Cq[q];
    }
    float part = 0.f;
#pragma unroll
    for (int i = 0; i < 16; i++) {
      hs[i] = hs[i] * dAv + dtx * Br[i];
      part += hs[i] * Cr[i];
    }
    s_part[cur][w][lane] = part;
    if (t + 1 < SEQL) {
      if (tid < 64) s_x[nxt][tid] = pre;
      else if (tid < 128) s_B[nxt][tid - 64] = pre;
      else if (tid < 192) s_C[nxt][tid - 128] = pre;
      else if (tid == 192) s_scal[nxt][0] = pre;
      else if (tid == 193) s_scal[nxt][1] = pre;
    }
    __syncthreads();
    if (w == 0) {
      float yv = s_part[cur][0][lane] + s_part[cur][1][lane] + s_part[cur][2][lane] +
                 s_part[cur][3][lane] + Dh * xv;
      y[(tok0 + t) * DINNER + h * 64 + lane] = __float2bfloat16(yv);
    }
  }
}

// ---------------- gated RMSNorm (in-place on y) ----------------
__global__ __launch_bounds__(256) void norm_kernel(
    bf16* __restrict__ y, const bf16* __restrict__ z,
    const float* __restrict__ norm_w) {
  int token = blockIdx.x;
  int tid = threadIdx.x;
  bf16* yp = y + (size_t)token * DINNER;
  const bf16* zp = z + (size_t)token * DINNER;
  float vals[6];
  float ss = 0.f;
#pragma unroll
  for (int i = 0; i < 6; i++) {
    int c = tid + i * 256;
    float yv = __bfloat162float(yp[c]);
    float zv = __bfloat162float(zp[c]);
    float g = zv / (1.f + expf(-zv));
    float v = yv * g;
    vals[i] = v;
    ss += v * v;
  }
  for (int off = 32; off > 0; off >>= 1) ss += __shfl_down(ss, off);
  __shared__ float sred[4];
  if ((tid & 63) == 0) sred[tid >> 6] = ss;
  __syncthreads();
  float tot = sred[0] + sred[1] + sred[2] + sred[3];
  float scale = rsqrtf(tot / (float)DINNER + 1e-5f);
#pragma unroll
  for (int i = 0; i < 6; i++) {
    int c = tid + i * 256;
    yp[c] = __float2bfloat16(vals[i] * scale * norm_w[c]);
  }
}

// ---------------- launch ----------------
extern "C" void kernel_launch(void* const* d_in, const int* in_sizes, int n_in,
                              void* d_out, int out_size, void* d_ws, size_t ws_size,
                              hipStream_t stream) {
  const float* x = (const float*)d_in[0];
  const float* fus_w = (const float*)d_in[1];
  const float* fus_b = (const float*)d_in[2];
  const float* in_w[2] = {(const float*)d_in[3], (const float*)d_in[11]};
  const float* conv_w[2] = {(const float*)d_in[4], (const float*)d_in[12]};
  const float* conv_b[2] = {(const float*)d_in[5], (const float*)d_in[13]};
  const float* dt_bias[2] = {(const float*)d_in[6], (const float*)d_in[14]};
  const float* A_log[2] = {(const float*)d_in[7], (const float*)d_in[15]};
  const float* Dp[2] = {(const float*)d_in[8], (const float*)d_in[16]};
  const float* norm_w[2] = {(const float*)d_in[9], (const float*)d_in[17]};
  const float* out_w[2] = {(const float*)d_in[10], (const float*)d_in[18]};
  (void)in_sizes; (void)n_in;

  char* ws = (char*)d_ws;
  size_t off = 0;
  auto alloc = [&](size_t bytes) {
    size_t o = off;
    off = (off + bytes + 255) & ~(size_t)255;
    return o;
  };
  bf16* x_bf  = (bf16*)(ws + alloc((size_t)NTOK * DMODEL * 2));        // 25.2 MB
  bf16* w_in  = (bf16*)(ws + alloc((size_t)NROWS_XBC * DMODEL * 2));   //  4.9 MB
  bf16* wf1   = (bf16*)(ws + alloc((size_t)DMODEL * DMODEL * 2));      //  1.2 MB
  bf16* owT   = (bf16*)(ws + alloc((size_t)DINNER * DMODEL * 2));      //  2.4 MB
  bf16* wc    = (bf16*)(ws + alloc((size_t)DMODEL * DINNER * 2));      //  2.4 MB
  bf16* z     = (bf16*)(ws + alloc((size_t)NTOK * DINNER * 2));        // 50.3 MB
  bf16* xbcr  = (bf16*)(ws + alloc((size_t)NTOK * CONVDIM * 2));       // 54.5 MB (y aliases)
  bf16* xbcc  = (bf16*)(ws + alloc((size_t)NTOK * CONVDIM * 2));       // 54.5 MB
  float* dtb  = (float*)(ws + alloc((size_t)NTOK * HN * 4));           //  1.6 MB
  float* dab  = (float*)(ws + alloc((size_t)NTOK * HN * 4));           //  1.6 MB
  bf16* ybuf  = xbcr;  // alias: xbc_raw is dead after conv

  if (ws_size < off) {  // diagnostic: clean absmax(=max|ref|) failure, not a crash
    hipMemsetAsync(d_out, 0, (size_t)out_size * 4, stream);
    return;
  }

  cast_x_kernel<<<(NTOK * DMODEL) / 256, 256, 0, stream>>>(x, x_bf);

  for (int dir = 0; dir < 2; dir++) {
    // weights
    cast_kernel<<<(NROWS_XBC * DMODEL) / 256, 256, 0, stream>>>(in_w[dir], w_in);
    // in-proj: z (cols 0..1536) and xBC (in_w rows 1536..3200)
    gemm_bt<true><<<dim3(NTOK / 128, DINNER / 128), 256, 0, stream>>>(
        x_bf, w_in, z, DMODEL, DINNER, dir, 0, 0, nullptr);
    gemm_bt<true><<<dim3(NTOK / 128, CONVDIM / 128), 256, 0, stream>>>(
        x_bf, w_in + (size_t)DINNER * DMODEL, xbcr, DMODEL, CONVDIM, dir, 0, 0, nullptr);
    // exact fp32 dt/dA
    dt_kernel<<<NTOK, 256, 0, stream>>>(x, in_w[dir], dt_bias[dir], A_log[dir], dtb, dab, dir);
    // conv + silu
    conv_kernel<<<(NTOK * CONVDIM) / 256, 256, 0, stream>>>(xbcr, conv_w[dir], conv_b[dir], xbcc);
    // sequential scan (y overwrites xbc_raw region)
    scan_kernel<<<BATCHN * HN, 256, 0, stream>>>(xbcc, dtb, dab, Dp[dir], ybuf);
    // gated RMSNorm in-place
    norm_kernel<<<NTOK, 256, 0, stream>>>(ybuf, z, norm_w[dir]);
    // combined weight: wc[j,k] = sum_c fus_w[j, dir*768+c] * out_w[c,k]
    cast_strided_kernel<<<(DMODEL * DMODEL) / 256, 256, 0, stream>>>(
        fus_w + dir * DMODEL, wf1, DMODEL, 2 * DMODEL);
    transpose_ow_kernel<<<(DINNER * DMODEL) / 256, 256, 0, stream>>>(out_w[dir], owT);
    gemm_bt<true><<<dim3(DMODEL / 128, DINNER / 128), 256, 0, stream>>>(
        wf1, owT, wc, DMODEL, DINNER, 0, 0, 0, nullptr);
    // out-proj + fusion: d_out (+)= ynorm @ wc^T  (dir1 rows un-flipped, fp32 accum)
    gemm_bt<false><<<dim3(NTOK / 128, DMODEL / 128), 256, 0, stream>>>(
        ybuf, wc, d_out, DINNER, DMODEL, 0, dir, dir, dir == 0 ? fus_b : nullptr);
  }
}

// Round 3
// 3080.406 us; speedup vs baseline: 2.4945x; 2.4945x over previous
//
#include <hip/hip_runtime.h>
#include <hip/hip_bf16.h>

// BiMamba: bidirectional Mamba2 forward, MI355X/gfx950.
// Per direction: in-proj (bf16 MFMA GEMM, A-row flip for backward) -> exact fp32
// dt/log-decay -> chunked SSD scan:
//   A: per-(b,h,chunk) intra-chunk y + chunk-state G (conv+silu fused in)
//   B: 64-step inter-chunk state recurrence (fp32 regs, writes prefix states)
//   C: per-(b,h,chunk) inter-chunk y contribution (RMW)
// -> z GEMM -> gated RMSNorm -> combined out-proj+fusion GEMM into fp32 d_out.
// dt path fully fp32 (log-space decay; no exp/log round-trip, no -inf NaN).

#define BATCHN 4
#define SEQL 4096
#define DMODEL 768
#define DINNER 1536
#define DSTATE 64
#define HN 24
#define CONVDIM 1664          // DINNER + 2*DSTATE
#define NROWS_XBC 3200        // DINNER + CONVDIM (in_w rows GEMMed; dt rows excluded)
#define NTOK (BATCHN*SEQL)    // 16384
#define NCHUNK 64             // SEQL / 64

typedef short v8s __attribute__((ext_vector_type(8)));
typedef unsigned short v8u __attribute__((ext_vector_type(8)));
typedef float v4f __attribute__((ext_vector_type(4)));
typedef __hip_bfloat16 bf16;

__device__ __forceinline__ int flip_row(int r) {
  return (r & ~4095) | (4095 - (r & 4095));
}
__device__ __forceinline__ float us2f(unsigned short u) {
  return __uint_as_float(((unsigned int)u) << 16);
}
__device__ __forceinline__ unsigned short f2us(float f) {
  bf16 b = __float2bfloat16(f);
  return __builtin_bit_cast(unsigned short, b);
}

// ---------------- cast kernels ----------------

__global__ void cast_x_kernel(const float* __restrict__ x, bf16* __restrict__ xf) {
  int idx = blockIdx.x * 256 + threadIdx.x;
  xf[idx] = __float2bfloat16(x[idx]);
}

__global__ void cast_kernel(const float* __restrict__ src, bf16* __restrict__ dst) {
  int idx = blockIdx.x * 256 + threadIdx.x;
  dst[idx] = __float2bfloat16(src[idx]);
}

// dst[j*cols+m] = src[j*src_stride+m]  (extract fus_w half)
__global__ void cast_strided_kernel(const float* __restrict__ src, bf16* __restrict__ dst,
                                    int cols, int src_stride) {
  int idx = blockIdx.x * 256 + threadIdx.x;
  int j = idx / cols, m = idx % cols;
  dst[idx] = __float2bfloat16(src[(size_t)j * src_stride + m]);
}

// dst[k*768+c] = src[c*1536+k] (out_w -> owT)
__global__ void transpose_ow_kernel(const float* __restrict__ src, bf16* __restrict__ dst) {
  int idx = blockIdx.x * 256 + threadIdx.x;
  int k = idx / DMODEL, c = idx % DMODEL;
  dst[idx] = __float2bfloat16(src[(size_t)c * DINNER + k]);
}

// ---------------- bf16 MFMA GEMM: C[M,N] = A[M,K] @ B[N,K]^T ----------------
template <bool OUT_BF16>
__global__ __launch_bounds__(256) void gemm_bt(
    const bf16* __restrict__ A, const bf16* __restrict__ B, void* __restrict__ C,
    int K, int ldc, int flip_a, int flip_c, int accum, const float* __restrict__ bias) {
  int tid = threadIdx.x;
  int wave = tid >> 6, lane = tid & 63;
  int l15 = lane & 15, quad = lane >> 4;
  int m0 = blockIdx.x * 128 + (wave >> 1) * 64;
  int n0 = blockIdx.y * 128 + (wave & 1) * 64;
  const short* Ap = (const short*)A;
  const short* Bp = (const short*)B;
  v4f acc[4][4];
#pragma unroll
  for (int i = 0; i < 4; i++)
#pragma unroll
    for (int j = 0; j < 4; j++) acc[i][j] = {0.f, 0.f, 0.f, 0.f};

  int arow[4];
#pragma unroll
  for (int i = 0; i < 4; i++) {
    int r = m0 + i * 16 + l15;
    arow[i] = flip_a ? flip_row(r) : r;
  }

  for (int k0 = 0; k0 < K; k0 += 32) {
    v8s af[4], bfr[4];
#pragma unroll
    for (int i = 0; i < 4; i++) {
      af[i]  = *(const v8s*)(Ap + (size_t)arow[i] * K + k0 + quad * 8);
      bfr[i] = *(const v8s*)(Bp + (size_t)(n0 + i * 16 + l15) * K + k0 + quad * 8);
    }
#pragma unroll
    for (int i = 0; i < 4; i++)
#pragma unroll
      for (int j = 0; j < 4; j++)
        acc[i][j] = __builtin_amdgcn_mfma_f32_16x16x32_bf16(af[i], bfr[j], acc[i][j], 0, 0, 0);
  }

  float bv[4];
#pragma unroll
  for (int j = 0; j < 4; j++) bv[j] = bias ? bias[n0 + j * 16 + l15] : 0.f;

#pragma unroll
  for (int i = 0; i < 4; i++) {
#pragma unroll
    for (int r = 0; r < 4; r++) {
      int row = m0 + i * 16 + quad * 4 + r;
      int orow = flip_c ? flip_row(row) : row;
#pragma unroll
      for (int j = 0; j < 4; j++) {
        int col = n0 + j * 16 + l15;
        float v = acc[i][j][r] + bv[j];
        size_t off = (size_t)orow * ldc + col;
        if (OUT_BF16) {
          ((bf16*)C)[off] = __float2bfloat16(v);
        } else {
          float* Cf = (float*)C;
          if (accum) v += Cf[off];
          Cf[off] = v;
        }
      }
    }
  }
}

// ---------------- fp32 dt path ----------------
// Block per token: exact fp32 dots vs in_w rows 3200..3224; writes dt and
// LOG-decay dl = -dt*exp(A_log) (log-space: no underflow->NaN in chunk scans).
__global__ __launch_bounds__(256) void dt_kernel(
    const float* __restrict__ x, const float* __restrict__ in_w,
    const float* __restrict__ dt_bias, const float* __restrict__ A_log,
    float* __restrict__ dt_o, float* __restrict__ dl_o, int flip) {
  int token = blockIdx.x;
  int srow = flip ? flip_row(token) : token;
  __shared__ float sx[DMODEL];
  const float* xp = x + (size_t)srow * DMODEL;
  for (int i = threadIdx.x; i < DMODEL; i += 256) sx[i] = xp[i];
  __syncthreads();
  int w = threadIdx.x >> 6, lane = threadIdx.x & 63;
#pragma unroll
  for (int hh = 0; hh < 6; hh++) {
    int h = w * 6 + hh;
    const float* wp = in_w + (size_t)(NROWS_XBC + h) * DMODEL;
    float s = 0.f;
#pragma unroll
    for (int i = 0; i < 12; i++) {
      int k = lane + i * 64;
      s += sx[k] * wp[k];
    }
    for (int off = 32; off > 0; off >>= 1) s += __shfl_down(s, off);
    if (lane == 0) {
      float v = s + dt_bias[h];
      float dt = (v > 20.f) ? v : log1pf(expf(v));
      dt_o[(size_t)token * HN + h] = dt;
      dl_o[(size_t)token * HN + h] = -dt * expf(A_log[h]);
    }
  }
}

// ---------------- chunked SSD: intra-chunk kernel ----------------
// Block = (b*HN+h)*64 + chunk. Stages conv+silu'd x(head)/B/C for 64 tokens,
// computes la (inclusive cumsum of dl), W[t][s] = mask*exp(la_t-la_s)*dt_s*(C_t.B_s),
// y_intra[t][p] (+ D*x) -> Yblob bf16, G[p][n] chunk-state -> Gblob bf16,
// laq[blk] = exp(la_63).
__global__ __launch_bounds__(256) void chunk_intra_kernel(
    const bf16* __restrict__ xbcr, const float* __restrict__ conv_w,
    const float* __restrict__ conv_b, const float* __restrict__ dtb,
    const float* __restrict__ dlb, const float* __restrict__ Dp,
    bf16* __restrict__ Yblob, bf16* __restrict__ Gblob, float* __restrict__ laq) {
  int blk = blockIdx.x;
  int c = blk & 63, bh = blk >> 6;
  int h = bh % HN, b = bh / HN;
  int tid = threadIdx.x, lane = tid & 63, wv = tid >> 6;
  int tok0 = b * SEQL + c * 64;

  __shared__ float sX[64][65];   // [p][s] conv+silu x head slice (scalar reads, bank p+s)
  __shared__ float sB[64][68];   // [n][s] (float4 reads over s; 68*4B = 16B-mult)
  __shared__ float sC[64][65];   // [t][n]
  __shared__ union {
    float W[64][68];             // [t][s]
    unsigned short raw[67][194]; // staged raw bf16 (halo+64 tokens x 192 ch; stride 97 words)
  } sU;
  __shared__ float sla[64], sdt[64], sdG[64];

  // phase 1: coalesced raw staging (tokens c*64-3 .. c*64+63, 192 channels)
  for (int i = tid; i < 67 * 192; i += 256) {
    int c3 = i % 192, s67 = i / 192;
    int l = c * 64 + s67 - 3;
    unsigned short v = 0;
    if (l >= 0) {
      int ch = (c3 < 64) ? (h * 64 + c3) : (1536 + (c3 - 64));
      v = ((const unsigned short*)xbcr)[(size_t)(b * SEQL + l) * CONVDIM + ch];
    }
    sU.raw[s67][c3] = v;
  }
  __syncthreads();

  // phase 2: conv(width4)+silu into sX/sB/sC; wave0 also computes la/dt/decay
  for (int i = tid; i < 192 * 64; i += 256) {
    int s = i & 63, g = i >> 6;                  // g uniform per wave
    int ch = (g < 64) ? (h * 64 + g) : (1536 + (g - 64));
    float acc = conv_b[ch];
    const float* w4 = conv_w + ch * 4;
#pragma unroll
    for (int j = 0; j < 4; j++) acc += us2f(sU.raw[s + j][g]) * w4[j];
    float sv = acc / (1.f + __expf(-acc));
    if (g < 64) sX[g][s] = sv;
    else if (g < 128) sB[g - 64][s] = sv;
    else sC[s][g - 128] = sv;
  }
  if (wv == 0) {
    float dtv = dtb[(size_t)(tok0 + lane) * HN + h];
    float lg = dlb[(size_t)(tok0 + lane) * HN + h];  // log dA, finite, <= 0
#pragma unroll
    for (int d = 1; d < 64; d <<= 1) {
      float o = __shfl_up(lg, d);
      if (lane >= d) lg += o;
    }
    sla[lane] = lg;
    sdt[lane] = dtv;
    float la63 = __shfl(lg, 63);
    sdG[lane] = __expf(la63 - lg) * dtv;
    if (lane == 63) laq[blk] = __expf(la63);
  }
  __syncthreads();

  // phase 3: W[t][s] (overwrites raw union)
  {
    int t = tid >> 2, sg = tid & 3;
    float acc[16];
#pragma unroll
    for (int k = 0; k < 16; k++) acc[k] = 0.f;
    for (int n = 0; n < 64; n++) {
      float cv = sC[t][n];
      const float4* bp = (const float4*)&sB[n][sg * 16];
#pragma unroll
      for (int k = 0; k < 4; k++) {
        float4 b4 = bp[k];
        acc[k * 4 + 0] += cv * b4.x;
        acc[k * 4 + 1] += cv * b4.y;
        acc[k * 4 + 2] += cv * b4.z;
        acc[k * 4 + 3] += cv * b4.w;
      }
    }
    float la_t = sla[t];
#pragma unroll
    for (int k = 0; k < 16; k++) {
      int s = sg * 16 + k;
      float w = (s <= t) ? __expf(la_t - sla[s]) * sdt[s] * acc[k] : 0.f;
      sU.W[t][s] = w;
    }
  }
  __syncthreads();

  // phase 4: y_intra + G (per-lane x row in registers)
  {
    int p = lane;
    float xrow[64];
#pragma unroll
    for (int s = 0; s < 64; s++) xrow[s] = sX[p][s];
    float Dh = Dp[h];
    size_t ybase = (size_t)blk * 4096;
#pragma unroll 1
    for (int tt = 0; tt < 16; tt++) {
      int t = wv * 16 + tt;
      float acc = Dh * xrow[t];
      const float4* wp = (const float4*)&sU.W[t][0];
#pragma unroll
      for (int k = 0; k < 16; k++) {
        float4 w4 = wp[k];
        acc += w4.x * xrow[4 * k] + w4.y * xrow[4 * k + 1] +
               w4.z * xrow[4 * k + 2] + w4.w * xrow[4 * k + 3];
      }
      Yblob[ybase + (size_t)t * 64 + p] = __float2bfloat16(acc);
    }
    // fold decay*dt into xrow, then G[p][n]
#pragma unroll
    for (int s = 0; s < 64; s++) xrow[s] *= sdG[s];
    size_t gbase = (size_t)blk * 4096 + (size_t)p * 64;
#pragma unroll 1
    for (int nn = 0; nn < 16; nn++) {
      int n = wv * 16 + nn;
      float acc = 0.f;
      const float4* bp = (const float4*)&sB[n][0];
#pragma unroll
      for (int k = 0; k < 16; k++) {
        float4 b4 = bp[k];
        acc += b4.x * xrow[4 * k] + b4.y * xrow[4 * k + 1] +
               b4.z * xrow[4 * k + 2] + b4.w * xrow[4 * k + 3];
      }
      Gblob[gbase + n] = __float2bfloat16(acc);
    }
  }
}

// ---------------- chunked SSD: inter-chunk state recurrence ----------------
// 96 blocks (b*HN+h); thread owns S[p=tid>>2][n=(tid&3)*16 ..+16] in fp32 regs.
// Reads G_c, writes prefix state S_{c-1} in its place, updates S. No barriers.
__global__ __launch_bounds__(256) void state_scan_kernel(
    bf16* __restrict__ blob, const float* __restrict__ laq) {
  int bh = blockIdx.x;
  int tid = threadIdx.x;
  size_t base = (size_t)bh * 64 * 4096 + (size_t)(tid >> 2) * 64 + (size_t)(tid & 3) * 16;
  float S[16];
#pragma unroll
  for (int i = 0; i < 16; i++) S[i] = 0.f;
  for (int c = 0; c < 64; c++) {
    float q = laq[bh * 64 + c];
    unsigned short* gp = (unsigned short*)blob + base + (size_t)c * 4096;
    v8u ga = ((v8u*)gp)[0], gb = ((v8u*)gp)[1];
    v8u pa, pb;
#pragma unroll
    for (int i = 0; i < 8; i++) {
      pa[i] = f2us(S[i]);
      pb[i] = f2us(S[8 + i]);
    }
    ((v8u*)gp)[0] = pa;
    ((v8u*)gp)[1] = pb;
#pragma unroll
    for (int i = 0; i < 8; i++) {
      S[i] = q * S[i] + us2f(ga[i]);
      S[8 + i] = q * S[8 + i] + us2f(gb[i]);
    }
  }
}

// ---------------- chunked SSD: inter-chunk y contribution ----------------
// Block = (b*HN+h)*64 + chunk: y[t][p] += exp(la_t) * sum_n S_prev[p][n]*C_t[n]
__global__ __launch_bounds__(256) void chunk_inter_kernel(
    const bf16* __restrict__ xbcr, const float* __restrict__ conv_w,
    const float* __restrict__ conv_b, const float* __restrict__ dlb,
    const bf16* __restrict__ blob, bf16* __restrict__ Yblob) {
  int blk = blockIdx.x;
  int c = blk & 63, bh = blk >> 6;
  int h = bh % HN, b = bh / HN;
  int tid = threadIdx.x, lane = tid & 63, wv = tid >> 6;
  int tok0 = b * SEQL + c * 64;

  __shared__ float sCt[64][68];
  __shared__ unsigned short sRawC[67][66];
  __shared__ float sel[64];

  for (int i = tid; i < 67 * 64; i += 256) {
    int n = i & 63, s67 = i >> 6;
    int l = c * 64 + s67 - 3;
    unsigned short v = 0;
    if (l >= 0) v = ((const unsigned short*)xbcr)[(size_t)(b * SEQL + l) * CONVDIM + 1600 + n];
    sRawC[s67][n] = v;
  }
  if (wv == 0) {
    float lg = dlb[(size_t)(tok0 + lane) * HN + h];
#pragma unroll
    for (int d = 1; d < 64; d <<= 1) {
      float o = __shfl_up(lg, d);
      if (lane >= d) lg += o;
    }
    sel[lane] = __expf(lg);
  }
  __syncthreads();
  for (int i = tid; i < 4096; i += 256) {
    int n = i & 63, t = i >> 6;
    int ch = 1600 + n;
    float acc = conv_b[ch];
    const float* w4 = conv_w + ch * 4;
#pragma unroll
    for (int j = 0; j < 4; j++) acc += us2f(sRawC[t + j][n]) * w4[j];
    sCt[t][n] = acc / (1.f + __expf(-acc));
  }
  __syncthreads();

  int p = lane;
  const unsigned short* sp = (const unsigned short*)blob + (size_t)blk * 4096 + (size_t)p * 64;
  float Srow[64];
#pragma unroll
  for (int k = 0; k < 8; k++) {
    v8u v = ((const v8u*)sp)[k];
#pragma unroll
    for (int j = 0; j < 8; j++) Srow[k * 8 + j] = us2f(v[j]);
  }
#pragma unroll 1
  for (int tt = 0; tt < 16; tt++) {
    int t = wv * 16 + tt;
    float acc = 0.f;
    const float4* cp = (const float4*)&sCt[t][0];
#pragma unroll
    for (int k = 0; k < 16; k++) {
      float4 c4 = cp[k];
      acc += c4.x * Srow[4 * k] + c4.y * Srow[4 * k + 1] +
             c4.z * Srow[4 * k + 2] + c4.w * Srow[4 * k + 3];
    }
    size_t yi = (size_t)blk * 4096 + (size_t)t * 64 + p;
    float old = __bfloat162float(Yblob[yi]);
    Yblob[yi] = __float2bfloat16(old + sel[t] * acc);
  }
}

// ---------------- gated RMSNorm: blob y + z rows -> ynorm rows ----------------
__global__ __launch_bounds__(256) void norm_kernel(
    const bf16* __restrict__ Yblob, const bf16* __restrict__ z,
    const float* __restrict__ norm_w, bf16* __restrict__ out) {
  int token = blockIdx.x;
  int tid = threadIdx.x;
  int b = token >> 12, l = token & 4095, c = l >> 6, t = l & 63;
  const bf16* zp = z + (size_t)token * DINNER;
  float vals[6];
  float ss = 0.f;
#pragma unroll
  for (int i = 0; i < 6; i++) {
    int ch = tid + i * 256;
    int h = ch >> 6, p = ch & 63;
    size_t yi = ((((size_t)(b * HN + h)) * 64 + c) * 64 + t) * 64 + p;
    float yv = __bfloat162float(Yblob[yi]);
    float zv = __bfloat162float(zp[ch]);
    float g = zv / (1.f + __expf(-zv));
    float v = yv * g;
    vals[i] = v;
    ss += v * v;
  }
  for (int off = 32; off > 0; off >>= 1) ss += __shfl_down(ss, off);
  __shared__ float sred[4];
  if ((tid & 63) == 0) sred[tid >> 6] = ss;
  __syncthreads();
  float tot = sred[0] + sred[1] + sred[2] + sred[3];
  float scale = rsqrtf(tot / (float)DINNER + 1e-5f);
#pragma unroll
  for (int i = 0; i < 6; i++) {
    int ch = tid + i * 256;
    out[(size_t)token * DINNER + ch] = __float2bfloat16(vals[i] * scale * norm_w[ch]);
  }
}

// ---------------- launch ----------------
extern "C" void kernel_launch(void* const* d_in, const int* in_sizes, int n_in,
                              void* d_out, int out_size, void* d_ws, size_t ws_size,
                              hipStream_t stream) {
  const float* x = (const float*)d_in[0];
  const float* fus_w = (const float*)d_in[1];
  const float* fus_b = (const float*)d_in[2];
  const float* in_w[2] = {(const float*)d_in[3], (const float*)d_in[11]};
  const float* conv_w[2] = {(const float*)d_in[4], (const float*)d_in[12]};
  const float* conv_b[2] = {(const float*)d_in[5], (const float*)d_in[13]};
  const float* dt_bias[2] = {(const float*)d_in[6], (const float*)d_in[14]};
  const float* A_log[2] = {(const float*)d_in[7], (const float*)d_in[15]};
  const float* Dp[2] = {(const float*)d_in[8], (const float*)d_in[16]};
  const float* norm_w[2] = {(const float*)d_in[9], (const float*)d_in[17]};
  const float* out_w[2] = {(const float*)d_in[10], (const float*)d_in[18]};
  (void)in_sizes; (void)n_in;

  char* ws = (char*)d_ws;
  size_t off = 0;
  auto alloc = [&](size_t bytes) {
    size_t o = off;
    off = (off + bytes + 255) & ~(size_t)255;
    return o;
  };
  bf16* x_bf  = (bf16*)(ws + alloc((size_t)NTOK * DMODEL * 2));          // 25.2 MB
  bf16* w_in  = (bf16*)(ws + alloc((size_t)NROWS_XBC * DMODEL * 2));     //  4.9 MB
  bf16* wf1   = (bf16*)(ws + alloc((size_t)DMODEL * DMODEL * 2));        //  1.2 MB
  bf16* owT   = (bf16*)(ws + alloc((size_t)DINNER * DMODEL * 2));        //  2.4 MB
  bf16* wc    = (bf16*)(ws + alloc((size_t)DMODEL * DINNER * 2));        //  2.4 MB
  bf16* xbcr  = (bf16*)(ws + alloc((size_t)NTOK * CONVDIM * 2));         // 54.5 MB (ynorm aliases after use)
  float* dtb  = (float*)(ws + alloc((size_t)NTOK * HN * 4));             //  1.6 MB
  float* dlb  = (float*)(ws + alloc((size_t)NTOK * HN * 4));             //  1.6 MB
  float* laq  = (float*)(ws + alloc((size_t)BATCHN * HN * NCHUNK * 4));  //  0.02 MB
  bf16* Gblob = (bf16*)(ws + alloc((size_t)NTOK * DINNER * 2));          // 50.3 MB (z aliases after scan)
  bf16* Yblob = (bf16*)(ws + alloc((size_t)NTOK * DINNER * 2));          // 50.3 MB
  bf16* zbuf  = Gblob;  // z GEMM output reuses G/prefix blob (dead after chunk_inter)
  bf16* ynorm = xbcr;   // normalized y reuses xbcr (dead after chunk_inter)

  if (ws_size < off) {  // diagnostic: clean absmax(=max|ref|) failure, not a crash
    hipMemsetAsync(d_out, 0, (size_t)out_size * 4, stream);
    return;
  }

  cast_x_kernel<<<(NTOK * DMODEL) / 256, 256, 0, stream>>>(x, x_bf);

  for (int dir = 0; dir < 2; dir++) {
    cast_kernel<<<(NROWS_XBC * DMODEL) / 256, 256, 0, stream>>>(in_w[dir], w_in);
    // in-proj xBC part (in_w rows 1536..3200) -> xbcr
    gemm_bt<true><<<dim3(NTOK / 128, CONVDIM / 128), 256, 0, stream>>>(
        x_bf, w_in + (size_t)DINNER * DMODEL, xbcr, DMODEL, CONVDIM, dir, 0, 0, nullptr);
    // exact fp32 dt + log-decay
    dt_kernel<<<NTOK, 256, 0, stream>>>(x, in_w[dir], dt_bias[dir], A_log[dir], dtb, dlb, dir);
    // chunked SSD
    chunk_intra_kernel<<<BATCHN * HN * NCHUNK, 256, 0, stream>>>(
        xbcr, conv_w[dir], conv_b[dir], dtb, dlb, Dp[dir], Yblob, Gblob, laq);
    state_scan_kernel<<<BATCHN * HN, 256, 0, stream>>>(Gblob, laq);
    chunk_inter_kernel<<<BATCHN * HN * NCHUNK, 256, 0, stream>>>(
        xbcr, conv_w[dir], conv_b[dir], dlb, Gblob, Yblob);
    // in-proj z part (in_w rows 0..1536) -> zbuf (blob region, now dead)
    gemm_bt<true><<<dim3(NTOK / 128, DINNER / 128), 256, 0, stream>>>(
        x_bf, w_in, zbuf, DMODEL, DINNER, dir, 0, 0, nullptr);
    // gated RMSNorm -> ynorm rows (xbcr region, now dead)
    norm_kernel<<<NTOK, 256, 0, stream>>>(Yblob, zbuf, norm_w[dir], ynorm);
    // combined weight wc = fus_half @ out_w  (768x1536)
    cast_strided_kernel<<<(DMODEL * DMODEL) / 256, 256, 0, stream>>>(
        fus_w + dir * DMODEL, wf1, DMODEL, 2 * DMODEL);
    transpose_ow_kernel<<<(DINNER * DMODEL) / 256, 256, 0, stream>>>(out_w[dir], owT);
    gemm_bt<true><<<dim3(DMODEL / 128, DINNER / 128), 256, 0, stream>>>(
        wf1, owT, wc, DMODEL, DINNER, 0, 0, 0, nullptr);
    // out-proj + fusion: d_out (+)= ynorm @ wc^T (dir1 un-flips rows, accumulates)
    gemm_bt<false><<<dim3(NTOK / 128, DMODEL / 128), 256, 0, stream>>>(
        ynorm, wc, d_out, DINNER, DMODEL, 0, dir, dir, dir == 0 ? fus_b : nullptr);
  }
}

// Round 4
// 2077.232 us; speedup vs baseline: 3.6992x; 1.4829x over previous
//
#include <hip/hip_runtime.h>
#include <hip/hip_bf16.h>

// BiMamba: bidirectional Mamba2 forward, MI355X/gfx950.
// Per direction: in-proj (bf16 MFMA GEMM, A-row flip for backward) -> exact fp32
// dt/log-decay -> chunked SSD scan (all three 64^3 matmuls on MFMA):
//   A: per-(b,h,chunk) intra-chunk y + chunk-state G (conv+silu fused, bf16 LDS)
//   B: 64-step inter-chunk state recurrence (fp32 regs, writes prefix states)
//   C: per-(b,h,chunk) inter-chunk y contribution (MFMA, coalesced RMW)
// -> z GEMM -> gated RMSNorm -> combined out-proj+fusion GEMM into fp32 d_out.
// dt path fully fp32 (log-space decay; no exp/log round-trip, no -inf NaN).

#define BATCHN 4
#define SEQL 4096
#define DMODEL 768
#define DINNER 1536
#define DSTATE 64
#define HN 24
#define CONVDIM 1664          // DINNER + 2*DSTATE
#define NROWS_XBC 3200        // DINNER + CONVDIM (in_w rows GEMMed; dt rows excluded)
#define NTOK (BATCHN*SEQL)    // 16384
#define NCHUNK 64             // SEQL / 64
#define LS 72                 // LDS stride (shorts): 16B-aligned rows, even bank spread

typedef short v8s __attribute__((ext_vector_type(8)));
typedef unsigned short v8u __attribute__((ext_vector_type(8)));
typedef float v4f __attribute__((ext_vector_type(4)));
typedef __hip_bfloat16 bf16;

__device__ __forceinline__ int flip_row(int r) {
  return (r & ~4095) | (4095 - (r & 4095));
}
__device__ __forceinline__ float us2f(unsigned short u) {
  return __uint_as_float(((unsigned int)u) << 16);
}
__device__ __forceinline__ unsigned short f2us(float f) {
  bf16 b = __float2bfloat16(f);
  return __builtin_bit_cast(unsigned short, b);
}

// ---------------- cast kernels ----------------

__global__ void cast_x_kernel(const float* __restrict__ x, bf16* __restrict__ xf) {
  int idx = blockIdx.x * 256 + threadIdx.x;
  xf[idx] = __float2bfloat16(x[idx]);
}

__global__ void cast_kernel(const float* __restrict__ src, bf16* __restrict__ dst) {
  int idx = blockIdx.x * 256 + threadIdx.x;
  dst[idx] = __float2bfloat16(src[idx]);
}

// dst[j*cols+m] = src[j*src_stride+m]  (extract fus_w half)
__global__ void cast_strided_kernel(const float* __restrict__ src, bf16* __restrict__ dst,
                                    int cols, int src_stride) {
  int idx = blockIdx.x * 256 + threadIdx.x;
  int j = idx / cols, m = idx % cols;
  dst[idx] = __float2bfloat16(src[(size_t)j * src_stride + m]);
}

// dst[k*768+c] = src[c*1536+k] (out_w -> owT)
__global__ void transpose_ow_kernel(const float* __restrict__ src, bf16* __restrict__ dst) {
  int idx = blockIdx.x * 256 + threadIdx.x;
  int k = idx / DMODEL, c = idx % DMODEL;
  dst[idx] = __float2bfloat16(src[(size_t)c * DINNER + k]);
}

// ---------------- bf16 MFMA GEMM: C[M,N] = A[M,K] @ B[N,K]^T ----------------
template <bool OUT_BF16>
__global__ __launch_bounds__(256) void gemm_bt(
    const bf16* __restrict__ A, const bf16* __restrict__ B, void* __restrict__ C,
    int K, int ldc, int flip_a, int flip_c, int accum, const float* __restrict__ bias) {
  int tid = threadIdx.x;
  int wave = tid >> 6, lane = tid & 63;
  int l15 = lane & 15, quad = lane >> 4;
  int m0 = blockIdx.x * 128 + (wave >> 1) * 64;
  int n0 = blockIdx.y * 128 + (wave & 1) * 64;
  const short* Ap = (const short*)A;
  const short* Bp = (const short*)B;
  v4f acc[4][4];
#pragma unroll
  for (int i = 0; i < 4; i++)
#pragma unroll
    for (int j = 0; j < 4; j++) acc[i][j] = {0.f, 0.f, 0.f, 0.f};

  int arow[4];
#pragma unroll
  for (int i = 0; i < 4; i++) {
    int r = m0 + i * 16 + l15;
    arow[i] = flip_a ? flip_row(r) : r;
  }

  for (int k0 = 0; k0 < K; k0 += 32) {
    v8s af[4], bfr[4];
#pragma unroll
    for (int i = 0; i < 4; i++) {
      af[i]  = *(const v8s*)(Ap + (size_t)arow[i] * K + k0 + quad * 8);
      bfr[i] = *(const v8s*)(Bp + (size_t)(n0 + i * 16 + l15) * K + k0 + quad * 8);
    }
#pragma unroll
    for (int i = 0; i < 4; i++)
#pragma unroll
      for (int j = 0; j < 4; j++)
        acc[i][j] = __builtin_amdgcn_mfma_f32_16x16x32_bf16(af[i], bfr[j], acc[i][j], 0, 0, 0);
  }

  float bv[4];
#pragma unroll
  for (int j = 0; j < 4; j++) bv[j] = bias ? bias[n0 + j * 16 + l15] : 0.f;

#pragma unroll
  for (int i = 0; i < 4; i++) {
#pragma unroll
    for (int r = 0; r < 4; r++) {
      int row = m0 + i * 16 + quad * 4 + r;
      int orow = flip_c ? flip_row(row) : row;
#pragma unroll
      for (int j = 0; j < 4; j++) {
        int col = n0 + j * 16 + l15;
        float v = acc[i][j][r] + bv[j];
        size_t off = (size_t)orow * ldc + col;
        if (OUT_BF16) {
          ((bf16*)C)[off] = __float2bfloat16(v);
        } else {
          float* Cf = (float*)C;
          if (accum) v += Cf[off];
          Cf[off] = v;
        }
      }
    }
  }
}

// ---------------- fp32 dt path ----------------
__global__ __launch_bounds__(256) void dt_kernel(
    const float* __restrict__ x, const float* __restrict__ in_w,
    const float* __restrict__ dt_bias, const float* __restrict__ A_log,
    float* __restrict__ dt_o, float* __restrict__ dl_o, int flip) {
  int token = blockIdx.x;
  int srow = flip ? flip_row(token) : token;
  __shared__ float sx[DMODEL];
  const float* xp = x + (size_t)srow * DMODEL;
  for (int i = threadIdx.x; i < DMODEL; i += 256) sx[i] = xp[i];
  __syncthreads();
  int w = threadIdx.x >> 6, lane = threadIdx.x & 63;
#pragma unroll
  for (int hh = 0; hh < 6; hh++) {
    int h = w * 6 + hh;
    const float* wp = in_w + (size_t)(NROWS_XBC + h) * DMODEL;
    float s = 0.f;
#pragma unroll
    for (int i = 0; i < 12; i++) {
      int k = lane + i * 64;
      s += sx[k] * wp[k];
    }
    for (int off = 32; off > 0; off >>= 1) s += __shfl_down(s, off);
    if (lane == 0) {
      float v = s + dt_bias[h];
      float dt = (v > 20.f) ? v : log1pf(expf(v));
      dt_o[(size_t)token * HN + h] = dt;
      dl_o[(size_t)token * HN + h] = -dt * expf(A_log[h]);
    }
  }
}

// ---------------- chunked SSD: intra-chunk kernel (MFMA) ----------------
// Block = (b*HN+h)*64 + chunk. Conv+silu'd bf16 operands in LDS; three MFMA
// matmuls: W = C@B^T (masked exp decay, dt), y = W@X + D*x, G = X@(dG*B).
// Coalesced dword copy-out of Y and G.
__global__ __launch_bounds__(256) void chunk_intra_kernel(
    const bf16* __restrict__ xbcr, const float* __restrict__ conv_w,
    const float* __restrict__ conv_b, const float* __restrict__ dtb,
    const float* __restrict__ dlb, const float* __restrict__ Dp,
    bf16* __restrict__ Yblob, bf16* __restrict__ Gblob, float* __restrict__ laq) {
  int blk = blockIdx.x;
  int c = blk & 63, bh = blk >> 6;
  int h = bh % HN, b = bh / HN;
  int tid = threadIdx.x, lane = tid & 63, wv = tid >> 6;
  int l15 = lane & 15, quad = lane >> 4;
  int tok0 = b * SEQL + c * 64;

  __shared__ unsigned short sXT[64][LS];  // [p][s]  x silu (A for G, B for y)
  __shared__ unsigned short sB [64][LS];  // [s][n]  B silu (B for W); later sY [t][p]
  __shared__ unsigned short sBT[64][LS];  // [n][s]  dG[s]*B (B for G)
  __shared__ unsigned short sC [64][LS];  // [t][n]  C silu (A for W); later sG [p][n]
  __shared__ union { unsigned short raw[67][194]; unsigned short W[64][LS]; } sU;
  __shared__ float sla[64], sdt[64], sdG[64];
  __shared__ float scwB[4][128], scbB[128];

  // phase 1: stage raw bf16 (halo+64 tokens x 192 ch) + B/C conv params
  for (int i = tid; i < 67 * 192; i += 256) {
    int c3 = i % 192, s67 = i / 192;
    int l = c * 64 + s67 - 3;
    unsigned short v = 0;
    if (l >= 0) {
      int ch = (c3 < 64) ? (h * 64 + c3) : (1536 + (c3 - 64));
      v = ((const unsigned short*)xbcr)[(size_t)(b * SEQL + l) * CONVDIM + ch];
    }
    sU.raw[s67][c3] = v;
  }
  if (tid < 128) {
    int ch = 1536 + tid;
#pragma unroll
    for (int j = 0; j < 4; j++) scwB[j][tid] = conv_w[ch * 4 + j];
    scbB[tid] = conv_b[ch];
  }
  __syncthreads();

  // phase 2: conv+silu -> bf16 LDS operands; wave0 prefix-scan of log-decay
  float Dh = Dp[h];
  {
    int s = tid & 63;
#pragma unroll
    for (int it = 0; it < 16; it++) {  // X part -> sXT[p][s]
      int p = (tid >> 6) + it * 4;
      int ch = h * 64 + p;
      float acc = conv_b[ch];
      const float* w4 = conv_w + ch * 4;
#pragma unroll
      for (int j = 0; j < 4; j++) acc += us2f(sU.raw[s + j][p]) * w4[j];
      sXT[p][s] = f2us(acc / (1.f + __expf(-acc)));
    }
    int n = tid & 63;
#pragma unroll
    for (int it = 0; it < 16; it++) {  // B part -> sB[s][n]
      int s2 = (tid >> 6) + it * 4;
      float acc = scbB[n];
#pragma unroll
      for (int j = 0; j < 4; j++) acc += us2f(sU.raw[s2 + j][64 + n]) * scwB[j][n];
      sB[s2][n] = f2us(acc / (1.f + __expf(-acc)));
    }
#pragma unroll
    for (int it = 0; it < 16; it++) {  // C part -> sC[t][n]
      int t = (tid >> 6) + it * 4;
      float acc = scbB[64 + n];
#pragma unroll
      for (int j = 0; j < 4; j++) acc += us2f(sU.raw[t + j][128 + n]) * scwB[j][64 + n];
      sC[t][n] = f2us(acc / (1.f + __expf(-acc)));
    }
  }
  if (wv == 0) {
    float dtv = dtb[(size_t)(tok0 + lane) * HN + h];
    float lg = dlb[(size_t)(tok0 + lane) * HN + h];  // log dA, finite, <= 0
#pragma unroll
    for (int d = 1; d < 64; d <<= 1) {
      float o = __shfl_up(lg, d);
      if (lane >= d) lg += o;
    }
    sla[lane] = lg;
    sdt[lane] = dtv;
    float la63 = __shfl(lg, 63);
    sdG[lane] = __expf(la63 - lg) * dtv;
    if (lane == 63) laq[blk] = __expf(la63);
  }
  __syncthreads();

  // phase 2b: sBT[n][s] = dG[s] * B[s][n]
  {
    int s = tid & 63;
#pragma unroll
    for (int it = 0; it < 16; it++) {
      int n = (tid >> 6) + it * 4;
      sBT[n][s] = f2us(us2f(sB[s][n]) * sdG[s]);
    }
  }
  __syncthreads();

  // phase 3: W = C @ B^T (MFMA), then mask * exp(la_t - la_s) * dt_s -> sU.W bf16
  {
    v4f acc[4];
#pragma unroll
    for (int j = 0; j < 4; j++) acc[j] = {0.f, 0.f, 0.f, 0.f};
#pragma unroll
    for (int k0 = 0; k0 < 2; k0++) {
      v8s a = *(const v8s*)&sC[16 * wv + l15][k0 * 32 + quad * 8];
#pragma unroll
      for (int j = 0; j < 4; j++) {
        v8s bb = *(const v8s*)&sB[16 * j + l15][k0 * 32 + quad * 8];
        acc[j] = __builtin_amdgcn_mfma_f32_16x16x32_bf16(a, bb, acc[j], 0, 0, 0);
      }
    }
    float lat[4];
#pragma unroll
    for (int r = 0; r < 4; r++) lat[r] = sla[16 * wv + quad * 4 + r];
#pragma unroll
    for (int j = 0; j < 4; j++) {
      int s = 16 * j + l15;
      float las = sla[s], dts = sdt[s];
#pragma unroll
      for (int r = 0; r < 4; r++) {
        int t = 16 * wv + quad * 4 + r;
        float w = (s <= t) ? __expf(lat[r] - las) * dts * acc[j][r] : 0.f;
        sU.W[t][s] = f2us(w);
      }
    }
  }
  __syncthreads();

  // phase 4: y = W @ X + D*x -> sY(=sB); G = X @ BT -> sG(=sC)
  {
    v4f ya[4], ga[4];
#pragma unroll
    for (int j = 0; j < 4; j++) {
      ya[j] = {0.f, 0.f, 0.f, 0.f};
      ga[j] = {0.f, 0.f, 0.f, 0.f};
    }
#pragma unroll
    for (int k0 = 0; k0 < 2; k0++) {
      v8s aw = *(const v8s*)&sU.W[16 * wv + l15][k0 * 32 + quad * 8];
      v8s ax = *(const v8s*)&sXT[16 * wv + l15][k0 * 32 + quad * 8];
#pragma unroll
      for (int j = 0; j < 4; j++) {
        v8s bx = *(const v8s*)&sXT[16 * j + l15][k0 * 32 + quad * 8];
        v8s bt = *(const v8s*)&sBT[16 * j + l15][k0 * 32 + quad * 8];
        ya[j] = __builtin_amdgcn_mfma_f32_16x16x32_bf16(aw, bx, ya[j], 0, 0, 0);
        ga[j] = __builtin_amdgcn_mfma_f32_16x16x32_bf16(ax, bt, ga[j], 0, 0, 0);
      }
    }
#pragma unroll
    for (int j = 0; j < 4; j++) {
      int col = 16 * j + l15;  // p for y, n for G
#pragma unroll
      for (int r = 0; r < 4; r++) {
        int row = 16 * wv + quad * 4 + r;  // t for y, p for G
        float yv = ya[j][r] + Dh * us2f(sXT[col][row]);
        sB[row][col] = f2us(yv);          // sY[t][p]
        sC[row][col] = f2us(ga[j][r]);    // sG[p][n]
      }
    }
  }
  __syncthreads();

  // phase 5: coalesced dword copy-out
  {
    unsigned int* gY = (unsigned int*)(Yblob + (size_t)blk * 4096);
    unsigned int* gG = (unsigned int*)(Gblob + (size_t)blk * 4096);
#pragma unroll
    for (int it = 0; it < 8; it++) {
      int d = tid + it * 256;
      int row = d >> 5, col2 = d & 31;
      gY[row * 32 + col2] = *(const unsigned int*)&sB[row][col2 * 2];
      gG[row * 32 + col2] = *(const unsigned int*)&sC[row][col2 * 2];
    }
  }
}

// ---------------- chunked SSD: inter-chunk state recurrence ----------------
__global__ __launch_bounds__(256) void state_scan_kernel(
    bf16* __restrict__ blob, const float* __restrict__ laq) {
  int bh = blockIdx.x;
  int tid = threadIdx.x;
  size_t base = (size_t)bh * 64 * 4096 + (size_t)(tid >> 2) * 64 + (size_t)(tid & 3) * 16;
  float S[16];
#pragma unroll
  for (int i = 0; i < 16; i++) S[i] = 0.f;
  for (int c = 0; c < 64; c++) {
    float q = laq[bh * 64 + c];
    unsigned short* gp = (unsigned short*)blob + base + (size_t)c * 4096;
    v8u ga = ((v8u*)gp)[0], gb = ((v8u*)gp)[1];
    v8u pa, pb;
#pragma unroll
    for (int i = 0; i < 8; i++) {
      pa[i] = f2us(S[i]);
      pb[i] = f2us(S[8 + i]);
    }
    ((v8u*)gp)[0] = pa;
    ((v8u*)gp)[1] = pb;
#pragma unroll
    for (int i = 0; i < 8; i++) {
      S[i] = q * S[i] + us2f(ga[i]);
      S[8 + i] = q * S[8 + i] + us2f(gb[i]);
    }
  }
}

// ---------------- chunked SSD: inter-chunk y contribution (MFMA) ----------------
// y[t][p] += sel[t] * sum_n C[t][n] * S_prev[p][n]; S fragments straight from global.
__global__ __launch_bounds__(256) void chunk_inter_kernel(
    const bf16* __restrict__ xbcr, const float* __restrict__ conv_w,
    const float* __restrict__ conv_b, const float* __restrict__ dlb,
    const bf16* __restrict__ blob, bf16* __restrict__ Yblob) {
  int blk = blockIdx.x;
  int c = blk & 63, bh = blk >> 6;
  int h = bh % HN, b = bh / HN;
  int tid = threadIdx.x, lane = tid & 63, wv = tid >> 6;
  int l15 = lane & 15, quad = lane >> 4;
  int tok0 = b * SEQL + c * 64;

  __shared__ unsigned short sRaw[67][66];
  __shared__ unsigned short sC[64][LS];   // [t][n]
  __shared__ unsigned short sY[64][LS];   // [t][p]
  __shared__ float sel[64];
  __shared__ float scw[4][64], scb[64];

  for (int i = tid; i < 67 * 64; i += 256) {
    int n = i & 63, s67 = i >> 6;
    int l = c * 64 + s67 - 3;
    unsigned short v = 0;
    if (l >= 0) v = ((const unsigned short*)xbcr)[(size_t)(b * SEQL + l) * CONVDIM + 1600 + n];
    sRaw[s67][n] = v;
  }
  if (tid < 64) {
    int ch = 1600 + tid;
#pragma unroll
    for (int j = 0; j < 4; j++) scw[j][tid] = conv_w[ch * 4 + j];
    scb[tid] = conv_b[ch];
  }
  if (wv == 0) {
    float lg = dlb[(size_t)(tok0 + lane) * HN + h];
#pragma unroll
    for (int d = 1; d < 64; d <<= 1) {
      float o = __shfl_up(lg, d);
      if (lane >= d) lg += o;
    }
    sel[lane] = __expf(lg);
  }
  __syncthreads();
  {
    int n = tid & 63;
#pragma unroll
    for (int it = 0; it < 16; it++) {
      int t = (tid >> 6) + it * 4;
      float acc = scb[n];
#pragma unroll
      for (int j = 0; j < 4; j++) acc += us2f(sRaw[t + j][n]) * scw[j][n];
      sC[t][n] = f2us(acc / (1.f + __expf(-acc)));
    }
  }
  __syncthreads();
  {
    v4f acc[4];
#pragma unroll
    for (int j = 0; j < 4; j++) acc[j] = {0.f, 0.f, 0.f, 0.f};
    const unsigned short* gS = (const unsigned short*)blob + (size_t)blk * 4096;
#pragma unroll
    for (int k0 = 0; k0 < 2; k0++) {
      v8s a = *(const v8s*)&sC[16 * wv + l15][k0 * 32 + quad * 8];
#pragma unroll
      for (int j = 0; j < 4; j++) {
        v8s bS = *(const v8s*)(gS + (size_t)(16 * j + l15) * 64 + k0 * 32 + quad * 8);
        acc[j] = __builtin_amdgcn_mfma_f32_16x16x32_bf16(a, bS, acc[j], 0, 0, 0);
      }
    }
    float selt[4];
#pragma unroll
    for (int r = 0; r < 4; r++) selt[r] = sel[16 * wv + quad * 4 + r];
#pragma unroll
    for (int j = 0; j < 4; j++)
#pragma unroll
      for (int r = 0; r < 4; r++)
        sY[16 * wv + quad * 4 + r][16 * j + l15] = f2us(selt[r] * acc[j][r]);
  }
  __syncthreads();
  {
    unsigned int* gY = (unsigned int*)(Yblob + (size_t)blk * 4096);
#pragma unroll
    for (int it = 0; it < 8; it++) {
      int d = tid + it * 256;
      int row = d >> 5, col2 = d & 31;
      unsigned int old = gY[row * 32 + col2];
      float lo = us2f((unsigned short)(old & 0xffff)) + us2f(sY[row][col2 * 2]);
      float hi = us2f((unsigned short)(old >> 16)) + us2f(sY[row][col2 * 2 + 1]);
      gY[row * 32 + col2] = (unsigned int)f2us(lo) | ((unsigned int)f2us(hi) << 16);
    }
  }
}

// ---------------- gated RMSNorm: blob y + z rows -> ynorm rows ----------------
__global__ __launch_bounds__(256) void norm_kernel(
    const bf16* __restrict__ Yblob, const bf16* __restrict__ z,
    const float* __restrict__ norm_w, bf16* __restrict__ out) {
  int token = blockIdx.x;
  int tid = threadIdx.x;
  int b = token >> 12, l = token & 4095, c = l >> 6, t = l & 63;
  const bf16* zp = z + (size_t)token * DINNER;
  float vals[6];
  float ss = 0.f;
#pragma unroll
  for (int i = 0; i < 6; i++) {
    int ch = tid + i * 256;
    int h = ch >> 6, p = ch & 63;
    size_t yi = ((((size_t)(b * HN + h)) * 64 + c) * 64 + t) * 64 + p;
    float yv = __bfloat162float(Yblob[yi]);
    float zv = __bfloat162float(zp[ch]);
    float g = zv / (1.f + __expf(-zv));
    float v = yv * g;
    vals[i] = v;
    ss += v * v;
  }
  for (int off = 32; off > 0; off >>= 1) ss += __shfl_down(ss, off);
  __shared__ float sred[4];
  if ((tid & 63) == 0) sred[tid >> 6] = ss;
  __syncthreads();
  float tot = sred[0] + sred[1] + sred[2] + sred[3];
  float scale = rsqrtf(tot / (float)DINNER + 1e-5f);
#pragma unroll
  for (int i = 0; i < 6; i++) {
    int ch = tid + i * 256;
    out[(size_t)token * DINNER + ch] = __float2bfloat16(vals[i] * scale * norm_w[ch]);
  }
}

// ---------------- launch ----------------
extern "C" void kernel_launch(void* const* d_in, const int* in_sizes, int n_in,
                              void* d_out, int out_size, void* d_ws, size_t ws_size,
                              hipStream_t stream) {
  const float* x = (const float*)d_in[0];
  const float* fus_w = (const float*)d_in[1];
  const float* fus_b = (const float*)d_in[2];
  const float* in_w[2] = {(const float*)d_in[3], (const float*)d_in[11]};
  const float* conv_w[2] = {(const float*)d_in[4], (const float*)d_in[12]};
  const float* conv_b[2] = {(const float*)d_in[5], (const float*)d_in[13]};
  const float* dt_bias[2] = {(const float*)d_in[6], (const float*)d_in[14]};
  const float* A_log[2] = {(const float*)d_in[7], (const float*)d_in[15]};
  const float* Dp[2] = {(const float*)d_in[8], (const float*)d_in[16]};
  const float* norm_w[2] = {(const float*)d_in[9], (const float*)d_in[17]};
  const float* out_w[2] = {(const float*)d_in[10], (const float*)d_in[18]};
  (void)in_sizes; (void)n_in;

  char* ws = (char*)d_ws;
  size_t off = 0;
  auto alloc = [&](size_t bytes) {
    size_t o = off;
    off = (off + bytes + 255) & ~(size_t)255;
    return o;
  };
  bf16* x_bf  = (bf16*)(ws + alloc((size_t)NTOK * DMODEL * 2));          // 25.2 MB
  bf16* w_in  = (bf16*)(ws + alloc((size_t)NROWS_XBC * DMODEL * 2));     //  4.9 MB
  bf16* wf1   = (bf16*)(ws + alloc((size_t)DMODEL * DMODEL * 2));        //  1.2 MB
  bf16* owT   = (bf16*)(ws + alloc((size_t)DINNER * DMODEL * 2));        //  2.4 MB
  bf16* wc    = (bf16*)(ws + alloc((size_t)DMODEL * DINNER * 2));        //  2.4 MB
  bf16* xbcr  = (bf16*)(ws + alloc((size_t)NTOK * CONVDIM * 2));         // 54.5 MB (ynorm aliases)
  float* dtb  = (float*)(ws + alloc((size_t)NTOK * HN * 4));             //  1.6 MB
  float* dlb  = (float*)(ws + alloc((size_t)NTOK * HN * 4));             //  1.6 MB
  float* laq  = (float*)(ws + alloc((size_t)BATCHN * HN * NCHUNK * 4));  //  0.02 MB
  bf16* Gblob = (bf16*)(ws + alloc((size_t)NTOK * DINNER * 2));          // 50.3 MB (z aliases)
  bf16* Yblob = (bf16*)(ws + alloc((size_t)NTOK * DINNER * 2));          // 50.3 MB
  bf16* zbuf  = Gblob;  // z GEMM output reuses G/prefix blob (dead after chunk_inter)
  bf16* ynorm = xbcr;   // normalized y reuses xbcr (dead after chunk_inter)

  if (ws_size < off) {  // diagnostic: clean absmax(=max|ref|) failure, not a crash
    hipMemsetAsync(d_out, 0, (size_t)out_size * 4, stream);
    return;
  }

  cast_x_kernel<<<(NTOK * DMODEL) / 256, 256, 0, stream>>>(x, x_bf);

  for (int dir = 0; dir < 2; dir++) {
    cast_kernel<<<(NROWS_XBC * DMODEL) / 256, 256, 0, stream>>>(in_w[dir], w_in);
    // in-proj xBC part (in_w rows 1536..3200) -> xbcr
    gemm_bt<true><<<dim3(NTOK / 128, CONVDIM / 128), 256, 0, stream>>>(
        x_bf, w_in + (size_t)DINNER * DMODEL, xbcr, DMODEL, CONVDIM, dir, 0, 0, nullptr);
    // exact fp32 dt + log-decay
    dt_kernel<<<NTOK, 256, 0, stream>>>(x, in_w[dir], dt_bias[dir], A_log[dir], dtb, dlb, dir);
    // chunked SSD
    chunk_intra_kernel<<<BATCHN * HN * NCHUNK, 256, 0, stream>>>(
        xbcr, conv_w[dir], conv_b[dir], dtb, dlb, Dp[dir], Yblob, Gblob, laq);
    state_scan_kernel<<<BATCHN * HN, 256, 0, stream>>>(Gblob, laq);
    chunk_inter_kernel<<<BATCHN * HN * NCHUNK, 256, 0, stream>>>(
        xbcr, conv_w[dir], conv_b[dir], dlb, Gblob, Yblob);
    // in-proj z part (in_w rows 0..1536) -> zbuf (blob region, now dead)
    gemm_bt<true><<<dim3(NTOK / 128, DINNER / 128), 256, 0, stream>>>(
        x_bf, w_in, zbuf, DMODEL, DINNER, dir, 0, 0, nullptr);
    // gated RMSNorm -> ynorm rows (xbcr region, now dead)
    norm_kernel<<<NTOK, 256, 0, stream>>>(Yblob, zbuf, norm_w[dir], ynorm);
    // combined weight wc = fus_half @ out_w  (768x1536)
    cast_strided_kernel<<<(DMODEL * DMODEL) / 256, 256, 0, stream>>>(
        fus_w + dir * DMODEL, wf1, DMODEL, 2 * DMODEL);
    transpose_ow_kernel<<<(DINNER * DMODEL) / 256, 256, 0, stream>>>(out_w[dir], owT);
    gemm_bt<true><<<dim3(DMODEL / 128, DINNER / 128), 256, 0, stream>>>(
        wf1, owT, wc, DMODEL, DINNER, 0, 0, 0, nullptr);
    // out-proj + fusion: d_out (+)= ynorm @ wc^T (dir1 un-flips rows, accumulates)
    gemm_bt<false><<<dim3(NTOK / 128, DMODEL / 128), 256, 0, stream>>>(
        ynorm, wc, d_out, DINNER, DMODEL, 0, dir, dir, dir == 0 ? fus_b : nullptr);
  }
}

// Round 5
// 1709.119 us; speedup vs baseline: 4.4960x; 1.2154x over previous
//
#include <hip/hip_runtime.h>
#include <hip/hip_bf16.h>

// BiMamba: bidirectional Mamba2 forward, MI355X/gfx950.
// Per direction: in-proj (bf16 MFMA GEMM, A-row flip for backward) -> exact fp32
// dt/log-decay -> conv+silu for B/C channels ONCE into per-chunk blobs ->
// chunked SSD scan (three 64^3 matmuls on MFMA):
//   A: per-(b,h,chunk) intra-chunk y + chunk-state G (X conv fused, B/C preconv'd)
//   B: 64-step inter-chunk state recurrence (fp32 regs, writes prefix states)
//   C: per-(b,h,chunk) inter-chunk y contribution (MFMA, coalesced RMW)
// -> z GEMM -> gated RMSNorm -> combined out-proj+fusion GEMM into fp32 d_out.
// dt path fully fp32 (log-space decay; no exp/log round-trip, no -inf NaN).

#define BATCHN 4
#define SEQL 4096
#define DMODEL 768
#define DINNER 1536
#define DSTATE 64
#define HN 24
#define CONVDIM 1664          // DINNER + 2*DSTATE
#define NROWS_XBC 3200        // DINNER + CONVDIM (in_w rows GEMMed; dt rows excluded)
#define NTOK (BATCHN*SEQL)    // 16384
#define NCHUNK 64             // SEQL / 64
#define LS 72                 // LDS stride (shorts): 16B-aligned rows

typedef short v8s __attribute__((ext_vector_type(8)));
typedef unsigned short v8u __attribute__((ext_vector_type(8)));
typedef float v4f __attribute__((ext_vector_type(4)));
typedef __hip_bfloat16 bf16;

__device__ __forceinline__ int flip_row(int r) {
  return (r & ~4095) | (4095 - (r & 4095));
}
__device__ __forceinline__ float us2f(unsigned short u) {
  return __uint_as_float(((unsigned int)u) << 16);
}
__device__ __forceinline__ unsigned short f2us(float f) {
  bf16 b = __float2bfloat16(f);
  return __builtin_bit_cast(unsigned short, b);
}

// ---------------- cast kernels ----------------

__global__ void cast_x_kernel(const float* __restrict__ x, bf16* __restrict__ xf) {
  int idx = blockIdx.x * 256 + threadIdx.x;
  xf[idx] = __float2bfloat16(x[idx]);
}

__global__ void cast_kernel(const float* __restrict__ src, bf16* __restrict__ dst) {
  int idx = blockIdx.x * 256 + threadIdx.x;
  dst[idx] = __float2bfloat16(src[idx]);
}

// dst[j*cols+m] = src[j*src_stride+m]  (extract fus_w half)
__global__ void cast_strided_kernel(const float* __restrict__ src, bf16* __restrict__ dst,
                                    int cols, int src_stride) {
  int idx = blockIdx.x * 256 + threadIdx.x;
  int j = idx / cols, m = idx % cols;
  dst[idx] = __float2bfloat16(src[(size_t)j * src_stride + m]);
}

// dst[k*768+c] = src[c*1536+k] (out_w -> owT)
__global__ void transpose_ow_kernel(const float* __restrict__ src, bf16* __restrict__ dst) {
  int idx = blockIdx.x * 256 + threadIdx.x;
  int k = idx / DMODEL, c = idx % DMODEL;
  dst[idx] = __float2bfloat16(src[(size_t)c * DINNER + k]);
}

// ---------------- bf16 MFMA GEMM: C[M,N] = A[M,K] @ B[N,K]^T ----------------
template <bool OUT_BF16>
__global__ __launch_bounds__(256) void gemm_bt(
    const bf16* __restrict__ A, const bf16* __restrict__ B, void* __restrict__ C,
    int K, int ldc, int flip_a, int flip_c, int accum, const float* __restrict__ bias) {
  int tid = threadIdx.x;
  int wave = tid >> 6, lane = tid & 63;
  int l15 = lane & 15, quad = lane >> 4;
  int m0 = blockIdx.x * 128 + (wave >> 1) * 64;
  int n0 = blockIdx.y * 128 + (wave & 1) * 64;
  const short* Ap = (const short*)A;
  const short* Bp = (const short*)B;
  v4f acc[4][4];
#pragma unroll
  for (int i = 0; i < 4; i++)
#pragma unroll
    for (int j = 0; j < 4; j++) acc[i][j] = {0.f, 0.f, 0.f, 0.f};

  int arow[4];
#pragma unroll
  for (int i = 0; i < 4; i++) {
    int r = m0 + i * 16 + l15;
    arow[i] = flip_a ? flip_row(r) : r;
  }

  for (int k0 = 0; k0 < K; k0 += 32) {
    v8s af[4], bfr[4];
#pragma unroll
    for (int i = 0; i < 4; i++) {
      af[i]  = *(const v8s*)(Ap + (size_t)arow[i] * K + k0 + quad * 8);
      bfr[i] = *(const v8s*)(Bp + (size_t)(n0 + i * 16 + l15) * K + k0 + quad * 8);
    }
#pragma unroll
    for (int i = 0; i < 4; i++)
#pragma unroll
      for (int j = 0; j < 4; j++)
        acc[i][j] = __builtin_amdgcn_mfma_f32_16x16x32_bf16(af[i], bfr[j], acc[i][j], 0, 0, 0);
  }

  float bv[4];
#pragma unroll
  for (int j = 0; j < 4; j++) bv[j] = bias ? bias[n0 + j * 16 + l15] : 0.f;

#pragma unroll
  for (int i = 0; i < 4; i++) {
#pragma unroll
    for (int r = 0; r < 4; r++) {
      int row = m0 + i * 16 + quad * 4 + r;
      int orow = flip_c ? flip_row(row) : row;
#pragma unroll
      for (int j = 0; j < 4; j++) {
        int col = n0 + j * 16 + l15;
        float v = acc[i][j][r] + bv[j];
        size_t off = (size_t)orow * ldc + col;
        if (OUT_BF16) {
          ((bf16*)C)[off] = __float2bfloat16(v);
        } else {
          float* Cf = (float*)C;
          if (accum) v += Cf[off];
          Cf[off] = v;
        }
      }
    }
  }
}

// ---------------- fp32 dt path ----------------
__global__ __launch_bounds__(256) void dt_kernel(
    const float* __restrict__ x, const float* __restrict__ in_w,
    const float* __restrict__ dt_bias, const float* __restrict__ A_log,
    float* __restrict__ dt_o, float* __restrict__ dl_o, int flip) {
  int token = blockIdx.x;
  int srow = flip ? flip_row(token) : token;
  __shared__ float sx[DMODEL];
  const float* xp = x + (size_t)srow * DMODEL;
  for (int i = threadIdx.x; i < DMODEL; i += 256) sx[i] = xp[i];
  __syncthreads();
  int w = threadIdx.x >> 6, lane = threadIdx.x & 63;
#pragma unroll
  for (int hh = 0; hh < 6; hh++) {
    int h = w * 6 + hh;
    const float* wp = in_w + (size_t)(NROWS_XBC + h) * DMODEL;
    float s = 0.f;
#pragma unroll
    for (int i = 0; i < 12; i++) {
      int k = lane + i * 64;
      s += sx[k] * wp[k];
    }
    for (int off = 32; off > 0; off >>= 1) s += __shfl_down(s, off);
    if (lane == 0) {
      float v = s + dt_bias[h];
      float dt = (v > 20.f) ? v : log1pf(expf(v));
      dt_o[(size_t)token * HN + h] = dt;
      dl_o[(size_t)token * HN + h] = -dt * expf(A_log[h]);
    }
  }
}

// ---------------- conv+silu for B/C channels -> per-chunk blobs ----------------
// Bblob/Cblob: [b][chunk][s][64] bf16. Done ONCE (was recomputed per-head).
__global__ void conv_bc_kernel(const bf16* __restrict__ xbcr,
                               const float* __restrict__ conv_w,
                               const float* __restrict__ conv_b,
                               bf16* __restrict__ Bblob, bf16* __restrict__ Cblob) {
  int idx = blockIdx.x * 256 + threadIdx.x;  // NTOK*128
  int token = idx >> 7, ch7 = idx & 127;
  int b = token >> 12, l = token & 4095, c = l >> 6, s = l & 63;
  int ch = 1536 + ch7;
  float acc = conv_b[ch];
  const float* w4 = conv_w + ch * 4;
#pragma unroll
  for (int j = 0; j < 4; j++) {
    int ls = l - 3 + j;
    if (ls >= 0)
      acc += __bfloat162float(xbcr[(size_t)((b << 12) | ls) * CONVDIM + ch]) * w4[j];
  }
  float v = acc / (1.f + __expf(-acc));
  size_t base = ((size_t)((b * 64 + c) * 64 + s)) * 64;
  if (ch7 < 64) Bblob[base + ch7] = __float2bfloat16(v);
  else          Cblob[base + (ch7 - 64)] = __float2bfloat16(v);
}

// ---------------- chunked SSD: intra-chunk kernel (MFMA) ----------------
// Block = (b*HN+h)*64 + chunk. X conv'd in-LDS; B/C loaded preconv'd from blobs.
// W = C@B^T (masked exp decay, dt), y = W@X + D*x, G = X@(dG*B^T).
__global__ __launch_bounds__(256) void chunk_intra_kernel(
    const bf16* __restrict__ xbcr, const bf16* __restrict__ Bblob,
    const bf16* __restrict__ Cblob, const float* __restrict__ conv_w,
    const float* __restrict__ conv_b, const float* __restrict__ dtb,
    const float* __restrict__ dlb, const float* __restrict__ Dp,
    bf16* __restrict__ Yblob, bf16* __restrict__ Gblob, float* __restrict__ laq) {
  int blk = blockIdx.x;
  int c = blk & 63, bh = blk >> 6;
  int h = bh % HN, b = bh / HN;
  int tid = threadIdx.x, lane = tid & 63, wv = tid >> 6;
  int l15 = lane & 15, quad = lane >> 4;
  int tok0 = b * SEQL + c * 64;

  __shared__ unsigned short sXT[64][LS];  // [p][s]  x silu (B for y; A for G after dG fold)
  __shared__ unsigned short sB [64][LS];  // [s][n]  B silu (B for W); later sY [t][p]
  __shared__ unsigned short sBT[64][LS];  // [n][s]  dG[s]*B (B for G)
  __shared__ unsigned short sC [64][LS];  // [t][n]  C silu (A for W); later sG [p][n]
  __shared__ union { unsigned short rawX[67][66]; unsigned short W[64][LS]; } sU;
  __shared__ float sla[64], sdt[64], sdG[64];

  // phase 1: stage raw X halo (67x64, coalesced) + B/C direct from blobs (v8u x2)
  for (int i = tid; i < 67 * 64; i += 256) {
    int p = i & 63, s67 = i >> 6;
    int l = c * 64 + s67 - 3;
    unsigned short v = 0;
    if (l >= 0)
      v = ((const unsigned short*)xbcr)[(size_t)(b * SEQL + l) * CONVDIM + h * 64 + p];
    sU.rawX[s67][p] = v;
  }
  {
    const v8u* gB = (const v8u*)((const unsigned short*)Bblob + ((size_t)(b * 64 + c)) * 4096);
    const v8u* gC = (const v8u*)((const unsigned short*)Cblob + ((size_t)(b * 64 + c)) * 4096);
    int r0 = tid >> 3, g0 = tid & 7;
#pragma unroll
    for (int it = 0; it < 2; it++) {
      int row = r0 + it * 32;
      *(v8u*)&sB[row][g0 * 8] = gB[row * 8 + g0];
      *(v8u*)&sC[row][g0 * 8] = gC[row * 8 + g0];
    }
  }
  if (wv == 0) {  // log-decay prefix scan
    float dtv = dtb[(size_t)(tok0 + lane) * HN + h];
    float lg = dlb[(size_t)(tok0 + lane) * HN + h];  // log dA, finite, <= 0
#pragma unroll
    for (int d = 1; d < 64; d <<= 1) {
      float o = __shfl_up(lg, d);
      if (lane >= d) lg += o;
    }
    sla[lane] = lg;
    sdt[lane] = dtv;
    float la63 = __shfl(lg, 63);
    sdG[lane] = __expf(la63 - lg) * dtv;
    if (lane == 63) laq[blk] = __expf(la63);
  }
  __syncthreads();

  // phase 2: X conv+silu -> sXT[p][s]; sBT[n][s] = dG[s]*B[s][n]
  float Dh = Dp[h];
  {
    int s = tid & 63;
#pragma unroll
    for (int it = 0; it < 16; it++) {
      int p = (tid >> 6) + it * 4;       // wave-uniform
      int ch = h * 64 + p;
      float acc = conv_b[ch];
      const float* w4 = conv_w + ch * 4; // wave-uniform -> scalar loads
#pragma unroll
      for (int j = 0; j < 4; j++) acc += us2f(sU.rawX[s + j][p]) * w4[j];
      sXT[p][s] = f2us(acc / (1.f + __expf(-acc)));
    }
#pragma unroll
    for (int it = 0; it < 16; it++) {
      int n = (tid >> 6) + it * 4;
      sBT[n][s] = f2us(us2f(sB[s][n]) * sdG[s]);
    }
  }
  __syncthreads();

  // phase 3: W = C @ B^T (MFMA), then mask * exp(la_t - la_s) * dt_s -> sU.W bf16
  {
    v4f acc[4];
#pragma unroll
    for (int j = 0; j < 4; j++) acc[j] = {0.f, 0.f, 0.f, 0.f};
#pragma unroll
    for (int k0 = 0; k0 < 2; k0++) {
      v8s a = *(const v8s*)&sC[16 * wv + l15][k0 * 32 + quad * 8];
#pragma unroll
      for (int j = 0; j < 4; j++) {
        v8s bb = *(const v8s*)&sB[16 * j + l15][k0 * 32 + quad * 8];
        acc[j] = __builtin_amdgcn_mfma_f32_16x16x32_bf16(a, bb, acc[j], 0, 0, 0);
      }
    }
    float lat[4];
#pragma unroll
    for (int r = 0; r < 4; r++) lat[r] = sla[16 * wv + quad * 4 + r];
#pragma unroll
    for (int j = 0; j < 4; j++) {
      int s = 16 * j + l15;
      float las = sla[s], dts = sdt[s];
#pragma unroll
      for (int r = 0; r < 4; r++) {
        int t = 16 * wv + quad * 4 + r;
        float w = (s <= t) ? __expf(lat[r] - las) * dts * acc[j][r] : 0.f;
        sU.W[t][s] = f2us(w);
      }
    }
  }
  __syncthreads();

  // phase 4: y = W @ X + D*x -> sY(=sB); G = X @ BT -> sG(=sC)
  {
    v4f ya[4], ga[4];
#pragma unroll
    for (int j = 0; j < 4; j++) {
      ya[j] = {0.f, 0.f, 0.f, 0.f};
      ga[j] = {0.f, 0.f, 0.f, 0.f};
    }
#pragma unroll
    for (int k0 = 0; k0 < 2; k0++) {
      v8s aw = *(const v8s*)&sU.W[16 * wv + l15][k0 * 32 + quad * 8];
      v8s ax = *(const v8s*)&sXT[16 * wv + l15][k0 * 32 + quad * 8];
#pragma unroll
      for (int j = 0; j < 4; j++) {
        v8s bx = *(const v8s*)&sXT[16 * j + l15][k0 * 32 + quad * 8];
        v8s bt = *(const v8s*)&sBT[16 * j + l15][k0 * 32 + quad * 8];
        ya[j] = __builtin_amdgcn_mfma_f32_16x16x32_bf16(aw, bx, ya[j], 0, 0, 0);
        ga[j] = __builtin_amdgcn_mfma_f32_16x16x32_bf16(ax, bt, ga[j], 0, 0, 0);
      }
    }
#pragma unroll
    for (int j = 0; j < 4; j++) {
      int col = 16 * j + l15;  // p for y, n for G
#pragma unroll
      for (int r = 0; r < 4; r++) {
        int row = 16 * wv + quad * 4 + r;  // t for y, p for G
        float yv = ya[j][r] + Dh * us2f(sXT[col][row]);
        sB[row][col] = f2us(yv);          // sY[t][p]
        sC[row][col] = f2us(ga[j][r]);    // sG[p][n]
      }
    }
  }
  __syncthreads();

  // phase 5: coalesced dword copy-out
  {
    unsigned int* gY = (unsigned int*)(Yblob + (size_t)blk * 4096);
    unsigned int* gG = (unsigned int*)(Gblob + (size_t)blk * 4096);
#pragma unroll
    for (int it = 0; it < 8; it++) {
      int d = tid + it * 256;
      int row = d >> 5, col2 = d & 31;
      gY[row * 32 + col2] = *(const unsigned int*)&sB[row][col2 * 2];
      gG[row * 32 + col2] = *(const unsigned int*)&sC[row][col2 * 2];
    }
  }
}

// ---------------- chunked SSD: inter-chunk state recurrence ----------------
__global__ __launch_bounds__(256) void state_scan_kernel(
    bf16* __restrict__ blob, const float* __restrict__ laq) {
  int bh = blockIdx.x;
  int tid = threadIdx.x;
  size_t base = (size_t)bh * 64 * 4096 + (size_t)(tid >> 2) * 64 + (size_t)(tid & 3) * 16;
  float S[16];
#pragma unroll
  for (int i = 0; i < 16; i++) S[i] = 0.f;
  for (int c = 0; c < 64; c++) {
    float q = laq[bh * 64 + c];
    unsigned short* gp = (unsigned short*)blob + base + (size_t)c * 4096;
    v8u ga = ((v8u*)gp)[0], gb = ((v8u*)gp)[1];
    v8u pa, pb;
#pragma unroll
    for (int i = 0; i < 8; i++) {
      pa[i] = f2us(S[i]);
      pb[i] = f2us(S[8 + i]);
    }
    ((v8u*)gp)[0] = pa;
    ((v8u*)gp)[1] = pb;
#pragma unroll
    for (int i = 0; i < 8; i++) {
      S[i] = q * S[i] + us2f(ga[i]);
      S[8 + i] = q * S[8 + i] + us2f(gb[i]);
    }
  }
}

// ---------------- chunked SSD: inter-chunk y contribution (MFMA) ----------------
// y[t][p] += sel[t] * sum_n C[t][n] * S_prev[p][n]; C preconv'd, S from global.
__global__ __launch_bounds__(256) void chunk_inter_kernel(
    const bf16* __restrict__ Cblob, const float* __restrict__ dlb,
    const bf16* __restrict__ blob, bf16* __restrict__ Yblob) {
  int blk = blockIdx.x;
  int c = blk & 63, bh = blk >> 6;
  int h = bh % HN, b = bh / HN;
  int tid = threadIdx.x, lane = tid & 63, wv = tid >> 6;
  int l15 = lane & 15, quad = lane >> 4;
  int tok0 = b * SEQL + c * 64;

  __shared__ unsigned short sC[64][LS];   // [t][n]
  __shared__ unsigned short sY[64][LS];   // [t][p]
  __shared__ float sel[64];

  {
    const v8u* gC = (const v8u*)((const unsigned short*)Cblob + ((size_t)(b * 64 + c)) * 4096);
    int r0 = tid >> 3, g0 = tid & 7;
#pragma unroll
    for (int it = 0; it < 2; it++) {
      int row = r0 + it * 32;
      *(v8u*)&sC[row][g0 * 8] = gC[row * 8 + g0];
    }
  }
  if (wv == 0) {
    float lg = dlb[(size_t)(tok0 + lane) * HN + h];
#pragma unroll
    for (int d = 1; d < 64; d <<= 1) {
      float o = __shfl_up(lg, d);
      if (lane >= d) lg += o;
    }
    sel[lane] = __expf(lg);
  }
  __syncthreads();
  {
    v4f acc[4];
#pragma unroll
    for (int j = 0; j < 4; j++) acc[j] = {0.f, 0.f, 0.f, 0.f};
    const unsigned short* gS = (const unsigned short*)blob + (size_t)blk * 4096;
#pragma unroll
    for (int k0 = 0; k0 < 2; k0++) {
      v8s a = *(const v8s*)&sC[16 * wv + l15][k0 * 32 + quad * 8];
#pragma unroll
      for (int j = 0; j < 4; j++) {
        v8s bS = *(const v8s*)(gS + (size_t)(16 * j + l15) * 64 + k0 * 32 + quad * 8);
        acc[j] = __builtin_amdgcn_mfma_f32_16x16x32_bf16(a, bS, acc[j], 0, 0, 0);
      }
    }
    float selt[4];
#pragma unroll
    for (int r = 0; r < 4; r++) selt[r] = sel[16 * wv + quad * 4 + r];
#pragma unroll
    for (int j = 0; j < 4; j++)
#pragma unroll
      for (int r = 0; r < 4; r++)
        sY[16 * wv + quad * 4 + r][16 * j + l15] = f2us(selt[r] * acc[j][r]);
  }
  __syncthreads();
  {
    unsigned int* gY = (unsigned int*)(Yblob + (size_t)blk * 4096);
#pragma unroll
    for (int it = 0; it < 8; it++) {
      int d = tid + it * 256;
      int row = d >> 5, col2 = d & 31;
      unsigned int old = gY[row * 32 + col2];
      float lo = us2f((unsigned short)(old & 0xffff)) + us2f(sY[row][col2 * 2]);
      float hi = us2f((unsigned short)(old >> 16)) + us2f(sY[row][col2 * 2 + 1]);
      gY[row * 32 + col2] = (unsigned int)f2us(lo) | ((unsigned int)f2us(hi) << 16);
    }
  }
}

// ---------------- gated RMSNorm: blob y + z rows -> ynorm rows ----------------
__global__ __launch_bounds__(256) void norm_kernel(
    const bf16* __restrict__ Yblob, const bf16* __restrict__ z,
    const float* __restrict__ norm_w, bf16* __restrict__ out) {
  int token = blockIdx.x;
  int tid = threadIdx.x;
  int b = token >> 12, l = token & 4095, c = l >> 6, t = l & 63;
  const bf16* zp = z + (size_t)token * DINNER;
  float vals[6];
  float ss = 0.f;
#pragma unroll
  for (int i = 0; i < 6; i++) {
    int ch = tid + i * 256;
    int h = ch >> 6, p = ch & 63;
    size_t yi = ((((size_t)(b * HN + h)) * 64 + c) * 64 + t) * 64 + p;
    float yv = __bfloat162float(Yblob[yi]);
    float zv = __bfloat162float(zp[ch]);
    float g = zv / (1.f + __expf(-zv));
    float v = yv * g;
    vals[i] = v;
    ss += v * v;
  }
  for (int off = 32; off > 0; off >>= 1) ss += __shfl_down(ss, off);
  __shared__ float sred[4];
  if ((tid & 63) == 0) sred[tid >> 6] = ss;
  __syncthreads();
  float tot = sred[0] + sred[1] + sred[2] + sred[3];
  float scale = rsqrtf(tot / (float)DINNER + 1e-5f);
#pragma unroll
  for (int i = 0; i < 6; i++) {
    int ch = tid + i * 256;
    out[(size_t)token * DINNER + ch] = __float2bfloat16(vals[i] * scale * norm_w[ch]);
  }
}

// ---------------- launch ----------------
extern "C" void kernel_launch(void* const* d_in, const int* in_sizes, int n_in,
                              void* d_out, int out_size, void* d_ws, size_t ws_size,
                              hipStream_t stream) {
  const float* x = (const float*)d_in[0];
  const float* fus_w = (const float*)d_in[1];
  const float* fus_b = (const float*)d_in[2];
  const float* in_w[2] = {(const float*)d_in[3], (const float*)d_in[11]};
  const float* conv_w[2] = {(const float*)d_in[4], (const float*)d_in[12]};
  const float* conv_b[2] = {(const float*)d_in[5], (const float*)d_in[13]};
  const float* dt_bias[2] = {(const float*)d_in[6], (const float*)d_in[14]};
  const float* A_log[2] = {(const float*)d_in[7], (const float*)d_in[15]};
  const float* Dp[2] = {(const float*)d_in[8], (const float*)d_in[16]};
  const float* norm_w[2] = {(const float*)d_in[9], (const float*)d_in[17]};
  const float* out_w[2] = {(const float*)d_in[10], (const float*)d_in[18]};
  (void)in_sizes; (void)n_in;

  char* ws = (char*)d_ws;
  size_t off = 0;
  auto alloc = [&](size_t bytes) {
    size_t o = off;
    off = (off + bytes + 255) & ~(size_t)255;
    return o;
  };
  bf16* x_bf  = (bf16*)(ws + alloc((size_t)NTOK * DMODEL * 2));          // 25.2 MB
  bf16* w_in  = (bf16*)(ws + alloc((size_t)NROWS_XBC * DMODEL * 2));     //  4.9 MB
  bf16* wf1   = (bf16*)(ws + alloc((size_t)DMODEL * DMODEL * 2));        //  1.2 MB
  bf16* owT   = (bf16*)(ws + alloc((size_t)DINNER * DMODEL * 2));        //  2.4 MB
  bf16* wc    = (bf16*)(ws + alloc((size_t)DMODEL * DINNER * 2));        //  2.4 MB
  bf16* xbcr  = (bf16*)(ws + alloc((size_t)NTOK * CONVDIM * 2));         // 54.5 MB (ynorm aliases)
  float* dtb  = (float*)(ws + alloc((size_t)NTOK * HN * 4));             //  1.6 MB
  float* dlb  = (float*)(ws + alloc((size_t)NTOK * HN * 4));             //  1.6 MB
  float* laq  = (float*)(ws + alloc((size_t)BATCHN * HN * NCHUNK * 4));  //  0.02 MB
  bf16* Bblob = (bf16*)(ws + alloc((size_t)NTOK * DSTATE * 2));          //  2.1 MB
  bf16* Cblob = (bf16*)(ws + alloc((size_t)NTOK * DSTATE * 2));          //  2.1 MB
  bf16* Gblob = (bf16*)(ws + alloc((size_t)NTOK * DINNER * 2));          // 50.3 MB (z aliases)
  bf16* Yblob = (bf16*)(ws + alloc((size_t)NTOK * DINNER * 2));          // 50.3 MB
  bf16* zbuf  = Gblob;  // z GEMM output reuses G/prefix blob (dead after chunk_inter)
  bf16* ynorm = xbcr;   // normalized y reuses xbcr (dead after chunk_inter)

  if (ws_size < off) {  // diagnostic: clean absmax(=max|ref|) failure, not a crash
    hipMemsetAsync(d_out, 0, (size_t)out_size * 4, stream);
    return;
  }

  cast_x_kernel<<<(NTOK * DMODEL) / 256, 256, 0, stream>>>(x, x_bf);

  for (int dir = 0; dir < 2; dir++) {
    cast_kernel<<<(NROWS_XBC * DMODEL) / 256, 256, 0, stream>>>(in_w[dir], w_in);
    // in-proj xBC part (in_w rows 1536..3200) -> xbcr
    gemm_bt<true><<<dim3(NTOK / 128, CONVDIM / 128), 256, 0, stream>>>(
        x_bf, w_in + (size_t)DINNER * DMODEL, xbcr, DMODEL, CONVDIM, dir, 0, 0, nullptr);
    // exact fp32 dt + log-decay
    dt_kernel<<<NTOK, 256, 0, stream>>>(x, in_w[dir], dt_bias[dir], A_log[dir], dtb, dlb, dir);
    // B/C conv+silu once -> per-chunk blobs
    conv_bc_kernel<<<(NTOK * 128) / 256, 256, 0, stream>>>(
        xbcr, conv_w[dir], conv_b[dir], Bblob, Cblob);
    // chunked SSD
    chunk_intra_kernel<<<BATCHN * HN * NCHUNK, 256, 0, stream>>>(
        xbcr, Bblob, Cblob, conv_w[dir], conv_b[dir], dtb, dlb, Dp[dir], Yblob, Gblob, laq);
    state_scan_kernel<<<BATCHN * HN, 256, 0, stream>>>(Gblob, laq);
    chunk_inter_kernel<<<BATCHN * HN * NCHUNK, 256, 0, stream>>>(Cblob, dlb, Gblob, Yblob);
    // in-proj z part (in_w rows 0..1536) -> zbuf (blob region, now dead)
    gemm_bt<true><<<dim3(NTOK / 128, DINNER / 128), 256, 0, stream>>>(
        x_bf, w_in, zbuf, DMODEL, DINNER, dir, 0, 0, nullptr);
    // gated RMSNorm -> ynorm rows (xbcr region, now dead)
    norm_kernel<<<NTOK, 256, 0, stream>>>(Yblob, zbuf, norm_w[dir], ynorm);
    // combined weight wc = fus_half @ out_w  (768x1536)
    cast_strided_kernel<<<(DMODEL * DMODEL) / 256, 256, 0, stream>>>(
        fus_w + dir * DMODEL, wf1, DMODEL, 2 * DMODEL);
    transpose_ow_kernel<<<(DINNER * DMODEL) / 256, 256, 0, stream>>>(out_w[dir], owT);
    gemm_bt<true><<<dim3(DMODEL / 128, DINNER / 128), 256, 0, stream>>>(
        wf1, owT, wc, DMODEL, DINNER, 0, 0, 0, nullptr);
    // out-proj + fusion: d_out (+)= ynorm @ wc^T (dir1 un-flips rows, accumulates)
    gemm_bt<false><<<dim3(NTOK / 128, DMODEL / 128), 256, 0, stream>>>(
        ynorm, wc, d_out, DINNER, DMODEL, 0, dir, dir, dir == 0 ? fus_b : nullptr);
  }
}

// Round 6
// 1229.076 us; speedup vs baseline: 6.2520x; 1.3906x over previous
//
#include <hip/hip_runtime.h>
#include <hip/hip_bf16.h>

// BiMamba: bidirectional Mamba2 forward, MI355X/gfx950.
// Per direction: in-proj (bf16 MFMA GEMM w/ global_load_lds staging, A-row flip
// for backward) -> exact fp32 dt/log-decay -> conv+silu for B/C once into
// per-chunk blobs -> chunked SSD scan (three 64^3 matmuls on MFMA):
//   A: per-(b,h,chunk) intra-chunk y + chunk-state G (X conv fused)
//   B: 64-step inter-chunk state recurrence (fp32 regs, writes prefix states)
//   C: per-(b,h,chunk) inter-chunk y contribution (MFMA, coalesced RMW)
// -> z GEMM -> gated RMSNorm -> combined out-proj+fusion GEMM into fp32 d_out.
// GEMM uses the m97 structure: 128x128 tile, BK=32, async global->LDS (16B),
// unpadded [row][32] LDS layout (lane-ordered for the wave-uniform LDS dest).

#define BATCHN 4
#define SEQL 4096
#define DMODEL 768
#define DINNER 1536
#define DSTATE 64
#define HN 24
#define CONVDIM 1664          // DINNER + 2*DSTATE
#define NROWS_XBC 3200        // DINNER + CONVDIM (in_w rows GEMMed; dt rows excluded)
#define NTOK (BATCHN*SEQL)    // 16384
#define NCHUNK 64             // SEQL / 64
#define LS 72                 // LDS stride (shorts) for chunk kernels

typedef short v8s __attribute__((ext_vector_type(8)));
typedef unsigned short v8u __attribute__((ext_vector_type(8)));
typedef float v4f __attribute__((ext_vector_type(4)));
typedef __hip_bfloat16 bf16;

__device__ __forceinline__ int flip_row(int r) {
  return (r & ~4095) | (4095 - (r & 4095));
}
__device__ __forceinline__ float us2f(unsigned short u) {
  return __uint_as_float(((unsigned int)u) << 16);
}
__device__ __forceinline__ unsigned short f2us(float f) {
  bf16 b = __float2bfloat16(f);
  return __builtin_bit_cast(unsigned short, b);
}
// async 16B/lane global->LDS; LDS dest = wave-uniform base + lane*16
__device__ __forceinline__ void async16(const unsigned short* g, unsigned short* l) {
  __builtin_amdgcn_global_load_lds(
      (const __attribute__((address_space(1))) unsigned int*)(const void*)g,
      (__attribute__((address_space(3))) unsigned int*)(void*)l, 16, 0, 0);
}

// ---------------- cast kernels ----------------

__global__ void cast_x_kernel(const float* __restrict__ x, bf16* __restrict__ xf) {
  int idx = blockIdx.x * 256 + threadIdx.x;
  xf[idx] = __float2bfloat16(x[idx]);
}

__global__ void cast_kernel(const float* __restrict__ src, bf16* __restrict__ dst) {
  int idx = blockIdx.x * 256 + threadIdx.x;
  dst[idx] = __float2bfloat16(src[idx]);
}

// dst[j*cols+m] = src[j*src_stride+m]  (extract fus_w half)
__global__ void cast_strided_kernel(const float* __restrict__ src, bf16* __restrict__ dst,
                                    int cols, int src_stride) {
  int idx = blockIdx.x * 256 + threadIdx.x;
  int j = idx / cols, m = idx % cols;
  dst[idx] = __float2bfloat16(src[(size_t)j * src_stride + m]);
}

// dst[k*768+c] = src[c*1536+k] (out_w -> owT)
__global__ void transpose_ow_kernel(const float* __restrict__ src, bf16* __restrict__ dst) {
  int idx = blockIdx.x * 256 + threadIdx.x;
  int k = idx / DMODEL, c = idx % DMODEL;
  dst[idx] = __float2bfloat16(src[(size_t)c * DINNER + k]);
}

// ------- bf16 MFMA GEMM, LDS-staged (m97 structure): C[M,N]=A[M,K]@B[N,K]^T -------
// 128x128 tile, BK=32. Staging: each wave issues 4 async16 (2 A-rows-of-16,
// 2 B-rows-of-16 segments); LDS layout [row][32] shorts, exactly lane-ordered.
// flip_a: per-lane global row reversal (free). Epilogue: bias/flip_c/accum.
template <bool OUT_BF16>
__global__ __launch_bounds__(256) void gemm_lds(
    const bf16* __restrict__ A, const bf16* __restrict__ B, void* __restrict__ C,
    int K, int ldc, int flip_a, int flip_c, int accum, const float* __restrict__ bias) {
  __shared__ unsigned short sA[128 * 32];
  __shared__ unsigned short sB[128 * 32];
  int tid = threadIdx.x;
  int wave = tid >> 6, lane = tid & 63;
  int l15 = lane & 15, quad = lane >> 4;
  int m0 = blockIdx.x * 128, n0 = blockIdx.y * 128;
  int mw = (wave >> 1) * 64, nw = (wave & 1) * 64;

  // staging addresses: wave w owns rows [w*32, w*32+32) of each tile
  int srow = wave * 32 + (lane >> 2);
  int scol = (lane & 3) * 8;
  const unsigned short* Ap = (const unsigned short*)A;
  const unsigned short* Bp = (const unsigned short*)B;
  int ar0 = m0 + srow, ar1 = m0 + srow + 16;
  if (flip_a) { ar0 = flip_row(ar0); ar1 = flip_row(ar1); }
  const unsigned short* ga0 = Ap + (size_t)ar0 * K + scol;
  const unsigned short* ga1 = Ap + (size_t)ar1 * K + scol;
  const unsigned short* gb0 = Bp + (size_t)(n0 + srow) * K + scol;
  const unsigned short* gb1 = Bp + (size_t)(n0 + srow + 16) * K + scol;
  unsigned short* lA0 = &sA[(wave * 32) * 32];        // wave-uniform bases
  unsigned short* lA1 = &sA[(wave * 32 + 16) * 32];
  unsigned short* lB0 = &sB[(wave * 32) * 32];
  unsigned short* lB1 = &sB[(wave * 32 + 16) * 32];

  v4f acc[4][4];
#pragma unroll
  for (int i = 0; i < 4; i++)
#pragma unroll
    for (int j = 0; j < 4; j++) acc[i][j] = {0.f, 0.f, 0.f, 0.f};

  for (int k0 = 0; k0 < K; k0 += 32) {
    async16(ga0 + k0, lA0);
    async16(ga1 + k0, lA1);
    async16(gb0 + k0, lB0);
    async16(gb1 + k0, lB1);
    __syncthreads();  // drains vmcnt -> staged tile visible
    v8s af[4], bfr[4];
#pragma unroll
    for (int i = 0; i < 4; i++)
      af[i] = *(const v8s*)&sA[(mw + i * 16 + l15) * 32 + quad * 8];
#pragma unroll
    for (int j = 0; j < 4; j++)
      bfr[j] = *(const v8s*)&sB[(nw + j * 16 + l15) * 32 + quad * 8];
#pragma unroll
    for (int i = 0; i < 4; i++)
#pragma unroll
      for (int j = 0; j < 4; j++)
        acc[i][j] = __builtin_amdgcn_mfma_f32_16x16x32_bf16(af[i], bfr[j], acc[i][j], 0, 0, 0);
    __syncthreads();  // all reads done before next stage overwrites
  }

  float bv[4];
#pragma unroll
  for (int j = 0; j < 4; j++) bv[j] = bias ? bias[n0 + nw + j * 16 + l15] : 0.f;

#pragma unroll
  for (int i = 0; i < 4; i++) {
#pragma unroll
    for (int r = 0; r < 4; r++) {
      int row = m0 + mw + i * 16 + quad * 4 + r;
      int orow = flip_c ? flip_row(row) : row;
#pragma unroll
      for (int j = 0; j < 4; j++) {
        int col = n0 + nw + j * 16 + l15;
        float v = acc[i][j][r] + bv[j];
        size_t off = (size_t)orow * ldc + col;
        if (OUT_BF16) {
          ((bf16*)C)[off] = __float2bfloat16(v);
        } else {
          float* Cf = (float*)C;
          if (accum) v += Cf[off];
          Cf[off] = v;
        }
      }
    }
  }
}

// ---------------- fp32 dt path ----------------
__global__ __launch_bounds__(256) void dt_kernel(
    const float* __restrict__ x, const float* __restrict__ in_w,
    const float* __restrict__ dt_bias, const float* __restrict__ A_log,
    float* __restrict__ dt_o, float* __restrict__ dl_o, int flip) {
  int token = blockIdx.x;
  int srow = flip ? flip_row(token) : token;
  __shared__ float sx[DMODEL];
  const float* xp = x + (size_t)srow * DMODEL;
  for (int i = threadIdx.x; i < DMODEL; i += 256) sx[i] = xp[i];
  __syncthreads();
  int w = threadIdx.x >> 6, lane = threadIdx.x & 63;
#pragma unroll
  for (int hh = 0; hh < 6; hh++) {
    int h = w * 6 + hh;
    const float* wp = in_w + (size_t)(NROWS_XBC + h) * DMODEL;
    float s = 0.f;
#pragma unroll
    for (int i = 0; i < 12; i++) {
      int k = lane + i * 64;
      s += sx[k] * wp[k];
    }
    for (int off = 32; off > 0; off >>= 1) s += __shfl_down(s, off);
    if (lane == 0) {
      float v = s + dt_bias[h];
      float dt = (v > 20.f) ? v : log1pf(expf(v));
      dt_o[(size_t)token * HN + h] = dt;
      dl_o[(size_t)token * HN + h] = -dt * expf(A_log[h]);
    }
  }
}

// ---------------- conv+silu for B/C channels -> per-chunk blobs ----------------
__global__ void conv_bc_kernel(const bf16* __restrict__ xbcr,
                               const float* __restrict__ conv_w,
                               const float* __restrict__ conv_b,
                               bf16* __restrict__ Bblob, bf16* __restrict__ Cblob) {
  int idx = blockIdx.x * 256 + threadIdx.x;  // NTOK*128
  int token = idx >> 7, ch7 = idx & 127;
  int b = token >> 12, l = token & 4095, c = l >> 6, s = l & 63;
  int ch = 1536 + ch7;
  float acc = conv_b[ch];
  const float* w4 = conv_w + ch * 4;
#pragma unroll
  for (int j = 0; j < 4; j++) {
    int ls = l - 3 + j;
    if (ls >= 0)
      acc += __bfloat162float(xbcr[(size_t)((b << 12) | ls) * CONVDIM + ch]) * w4[j];
  }
  float v = acc / (1.f + __expf(-acc));
  size_t base = ((size_t)((b * 64 + c) * 64 + s)) * 64;
  if (ch7 < 64) Bblob[base + ch7] = __float2bfloat16(v);
  else          Cblob[base + (ch7 - 64)] = __float2bfloat16(v);
}

// ---------------- chunked SSD: intra-chunk kernel (MFMA) ----------------
__global__ __launch_bounds__(256) void chunk_intra_kernel(
    const bf16* __restrict__ xbcr, const bf16* __restrict__ Bblob,
    const bf16* __restrict__ Cblob, const float* __restrict__ conv_w,
    const float* __restrict__ conv_b, const float* __restrict__ dtb,
    const float* __restrict__ dlb, const float* __restrict__ Dp,
    bf16* __restrict__ Yblob, bf16* __restrict__ Gblob, float* __restrict__ laq) {
  int blk = blockIdx.x;
  int c = blk & 63, bh = blk >> 6;
  int h = bh % HN, b = bh / HN;
  int tid = threadIdx.x, lane = tid & 63, wv = tid >> 6;
  int l15 = lane & 15, quad = lane >> 4;
  int tok0 = b * SEQL + c * 64;

  __shared__ unsigned short sXT[64][LS];  // [p][s]
  __shared__ unsigned short sB [64][LS];  // [s][n]; later sY [t][p]
  __shared__ unsigned short sBT[64][LS];  // [n][s] dG-scaled
  __shared__ unsigned short sC [64][LS];  // [t][n]; later sG [p][n]
  __shared__ union { unsigned short rawX[67][66]; unsigned short W[64][LS]; } sU;
  __shared__ float sla[64], sdt[64], sdG[64];

  for (int i = tid; i < 67 * 64; i += 256) {
    int p = i & 63, s67 = i >> 6;
    int l = c * 64 + s67 - 3;
    unsigned short v = 0;
    if (l >= 0)
      v = ((const unsigned short*)xbcr)[(size_t)(b * SEQL + l) * CONVDIM + h * 64 + p];
    sU.rawX[s67][p] = v;
  }
  {
    const v8u* gB = (const v8u*)((const unsigned short*)Bblob + ((size_t)(b * 64 + c)) * 4096);
    const v8u* gC = (const v8u*)((const unsigned short*)Cblob + ((size_t)(b * 64 + c)) * 4096);
    int r0 = tid >> 3, g0 = tid & 7;
#pragma unroll
    for (int it = 0; it < 2; it++) {
      int row = r0 + it * 32;
      *(v8u*)&sB[row][g0 * 8] = gB[row * 8 + g0];
      *(v8u*)&sC[row][g0 * 8] = gC[row * 8 + g0];
    }
  }
  if (wv == 0) {  // log-decay prefix scan
    float dtv = dtb[(size_t)(tok0 + lane) * HN + h];
    float lg = dlb[(size_t)(tok0 + lane) * HN + h];
#pragma unroll
    for (int d = 1; d < 64; d <<= 1) {
      float o = __shfl_up(lg, d);
      if (lane >= d) lg += o;
    }
    sla[lane] = lg;
    sdt[lane] = dtv;
    float la63 = __shfl(lg, 63);
    sdG[lane] = __expf(la63 - lg) * dtv;
    if (lane == 63) laq[blk] = __expf(la63);
  }
  __syncthreads();

  float Dh = Dp[h];
  {
    int s = tid & 63;
#pragma unroll
    for (int it = 0; it < 16; it++) {
      int p = (tid >> 6) + it * 4;
      int ch = h * 64 + p;
      float acc = conv_b[ch];
      const float* w4 = conv_w + ch * 4;
#pragma unroll
      for (int j = 0; j < 4; j++) acc += us2f(sU.rawX[s + j][p]) * w4[j];
      sXT[p][s] = f2us(acc / (1.f + __expf(-acc)));
    }
#pragma unroll
    for (int it = 0; it < 16; it++) {
      int n = (tid >> 6) + it * 4;
      sBT[n][s] = f2us(us2f(sB[s][n]) * sdG[s]);
    }
  }
  __syncthreads();

  {  // W = C @ B^T, masked decay
    v4f acc[4];
#pragma unroll
    for (int j = 0; j < 4; j++) acc[j] = {0.f, 0.f, 0.f, 0.f};
#pragma unroll
    for (int k0 = 0; k0 < 2; k0++) {
      v8s a = *(const v8s*)&sC[16 * wv + l15][k0 * 32 + quad * 8];
#pragma unroll
      for (int j = 0; j < 4; j++) {
        v8s bb = *(const v8s*)&sB[16 * j + l15][k0 * 32 + quad * 8];
        acc[j] = __builtin_amdgcn_mfma_f32_16x16x32_bf16(a, bb, acc[j], 0, 0, 0);
      }
    }
    float lat[4];
#pragma unroll
    for (int r = 0; r < 4; r++) lat[r] = sla[16 * wv + quad * 4 + r];
#pragma unroll
    for (int j = 0; j < 4; j++) {
      int s = 16 * j + l15;
      float las = sla[s], dts = sdt[s];
#pragma unroll
      for (int r = 0; r < 4; r++) {
        int t = 16 * wv + quad * 4 + r;
        float w = (s <= t) ? __expf(lat[r] - las) * dts * acc[j][r] : 0.f;
        sU.W[t][s] = f2us(w);
      }
    }
  }
  __syncthreads();

  {  // y = W @ X + D*x; G = X @ BT
    v4f ya[4], ga[4];
#pragma unroll
    for (int j = 0; j < 4; j++) {
      ya[j] = {0.f, 0.f, 0.f, 0.f};
      ga[j] = {0.f, 0.f, 0.f, 0.f};
    }
#pragma unroll
    for (int k0 = 0; k0 < 2; k0++) {
      v8s aw = *(const v8s*)&sU.W[16 * wv + l15][k0 * 32 + quad * 8];
      v8s ax = *(const v8s*)&sXT[16 * wv + l15][k0 * 32 + quad * 8];
#pragma unroll
      for (int j = 0; j < 4; j++) {
        v8s bx = *(const v8s*)&sXT[16 * j + l15][k0 * 32 + quad * 8];
        v8s bt = *(const v8s*)&sBT[16 * j + l15][k0 * 32 + quad * 8];
        ya[j] = __builtin_amdgcn_mfma_f32_16x16x32_bf16(aw, bx, ya[j], 0, 0, 0);
        ga[j] = __builtin_amdgcn_mfma_f32_16x16x32_bf16(ax, bt, ga[j], 0, 0, 0);
      }
    }
#pragma unroll
    for (int j = 0; j < 4; j++) {
      int col = 16 * j + l15;
#pragma unroll
      for (int r = 0; r < 4; r++) {
        int row = 16 * wv + quad * 4 + r;
        float yv = ya[j][r] + Dh * us2f(sXT[col][row]);
        sB[row][col] = f2us(yv);
        sC[row][col] = f2us(ga[j][r]);
      }
    }
  }
  __syncthreads();

  {
    unsigned int* gY = (unsigned int*)(Yblob + (size_t)blk * 4096);
    unsigned int* gG = (unsigned int*)(Gblob + (size_t)blk * 4096);
#pragma unroll
    for (int it = 0; it < 8; it++) {
      int d = tid + it * 256;
      int row = d >> 5, col2 = d & 31;
      gY[row * 32 + col2] = *(const unsigned int*)&sB[row][col2 * 2];
      gG[row * 32 + col2] = *(const unsigned int*)&sC[row][col2 * 2];
    }
  }
}

// ---------------- chunked SSD: inter-chunk state recurrence ----------------
__global__ __launch_bounds__(256) void state_scan_kernel(
    bf16* __restrict__ blob, const float* __restrict__ laq) {
  int bh = blockIdx.x;
  int tid = threadIdx.x;
  size_t base = (size_t)bh * 64 * 4096 + (size_t)(tid >> 2) * 64 + (size_t)(tid & 3) * 16;
  float S[16];
#pragma unroll
  for (int i = 0; i < 16; i++) S[i] = 0.f;
  for (int c = 0; c < 64; c++) {
    float q = laq[bh * 64 + c];
    unsigned short* gp = (unsigned short*)blob + base + (size_t)c * 4096;
    v8u ga = ((v8u*)gp)[0], gb = ((v8u*)gp)[1];
    v8u pa, pb;
#pragma unroll
    for (int i = 0; i < 8; i++) {
      pa[i] = f2us(S[i]);
      pb[i] = f2us(S[8 + i]);
    }
    ((v8u*)gp)[0] = pa;
    ((v8u*)gp)[1] = pb;
#pragma unroll
    for (int i = 0; i < 8; i++) {
      S[i] = q * S[i] + us2f(ga[i]);
      S[8 + i] = q * S[8 + i] + us2f(gb[i]);
    }
  }
}

// ---------------- chunked SSD: inter-chunk y contribution (MFMA) ----------------
__global__ __launch_bounds__(256) void chunk_inter_kernel(
    const bf16* __restrict__ Cblob, const float* __restrict__ dlb,
    const bf16* __restrict__ blob, bf16* __restrict__ Yblob) {
  int blk = blockIdx.x;
  int c = blk & 63, bh = blk >> 6;
  int h = bh % HN, b = bh / HN;
  int tid = threadIdx.x, lane = tid & 63, wv = tid >> 6;
  int l15 = lane & 15, quad = lane >> 4;
  int tok0 = b * SEQL + c * 64;

  __shared__ unsigned short sC[64][LS];
  __shared__ unsigned short sY[64][LS];
  __shared__ float sel[64];

  {
    const v8u* gC = (const v8u*)((const unsigned short*)Cblob + ((size_t)(b * 64 + c)) * 4096);
    int r0 = tid >> 3, g0 = tid & 7;
#pragma unroll
    for (int it = 0; it < 2; it++) {
      int row = r0 + it * 32;
      *(v8u*)&sC[row][g0 * 8] = gC[row * 8 + g0];
    }
  }
  if (wv == 0) {
    float lg = dlb[(size_t)(tok0 + lane) * HN + h];
#pragma unroll
    for (int d = 1; d < 64; d <<= 1) {
      float o = __shfl_up(lg, d);
      if (lane >= d) lg += o;
    }
    sel[lane] = __expf(lg);
  }
  __syncthreads();
  {
    v4f acc[4];
#pragma unroll
    for (int j = 0; j < 4; j++) acc[j] = {0.f, 0.f, 0.f, 0.f};
    const unsigned short* gS = (const unsigned short*)blob + (size_t)blk * 4096;
#pragma unroll
    for (int k0 = 0; k0 < 2; k0++) {
      v8s a = *(const v8s*)&sC[16 * wv + l15][k0 * 32 + quad * 8];
#pragma unroll
      for (int j = 0; j < 4; j++) {
        v8s bS = *(const v8s*)(gS + (size_t)(16 * j + l15) * 64 + k0 * 32 + quad * 8);
        acc[j] = __builtin_amdgcn_mfma_f32_16x16x32_bf16(a, bS, acc[j], 0, 0, 0);
      }
    }
    float selt[4];
#pragma unroll
    for (int r = 0; r < 4; r++) selt[r] = sel[16 * wv + quad * 4 + r];
#pragma unroll
    for (int j = 0; j < 4; j++)
#pragma unroll
      for (int r = 0; r < 4; r++)
        sY[16 * wv + quad * 4 + r][16 * j + l15] = f2us(selt[r] * acc[j][r]);
  }
  __syncthreads();
  {
    unsigned int* gY = (unsigned int*)(Yblob + (size_t)blk * 4096);
#pragma unroll
    for (int it = 0; it < 8; it++) {
      int d = tid + it * 256;
      int row = d >> 5, col2 = d & 31;
      unsigned int old = gY[row * 32 + col2];
      float lo = us2f((unsigned short)(old & 0xffff)) + us2f(sY[row][col2 * 2]);
      float hi = us2f((unsigned short)(old >> 16)) + us2f(sY[row][col2 * 2 + 1]);
      gY[row * 32 + col2] = (unsigned int)f2us(lo) | ((unsigned int)f2us(hi) << 16);
    }
  }
}

// ---------------- gated RMSNorm: blob y + z rows -> ynorm rows ----------------
__global__ __launch_bounds__(256) void norm_kernel(
    const bf16* __restrict__ Yblob, const bf16* __restrict__ z,
    const float* __restrict__ norm_w, bf16* __restrict__ out) {
  int token = blockIdx.x;
  int tid = threadIdx.x;
  int b = token >> 12, l = token & 4095, c = l >> 6, t = l & 63;
  const bf16* zp = z + (size_t)token * DINNER;
  float vals[6];
  float ss = 0.f;
#pragma unroll
  for (int i = 0; i < 6; i++) {
    int ch = tid + i * 256;
    int h = ch >> 6, p = ch & 63;
    size_t yi = ((((size_t)(b * HN + h)) * 64 + c) * 64 + t) * 64 + p;
    float yv = __bfloat162float(Yblob[yi]);
    float zv = __bfloat162float(zp[ch]);
    float g = zv / (1.f + __expf(-zv));
    float v = yv * g;
    vals[i] = v;
    ss += v * v;
  }
  for (int off = 32; off > 0; off >>= 1) ss += __shfl_down(ss, off);
  __shared__ float sred[4];
  if ((tid & 63) == 0) sred[tid >> 6] = ss;
  __syncthreads();
  float tot = sred[0] + sred[1] + sred[2] + sred[3];
  float scale = rsqrtf(tot / (float)DINNER + 1e-5f);
#pragma unroll
  for (int i = 0; i < 6; i++) {
    int ch = tid + i * 256;
    out[(size_t)token * DINNER + ch] = __float2bfloat16(vals[i] * scale * norm_w[ch]);
  }
}

// ---------------- launch ----------------
extern "C" void kernel_launch(void* const* d_in, const int* in_sizes, int n_in,
                              void* d_out, int out_size, void* d_ws, size_t ws_size,
                              hipStream_t stream) {
  const float* x = (const float*)d_in[0];
  const float* fus_w = (const float*)d_in[1];
  const float* fus_b = (const float*)d_in[2];
  const float* in_w[2] = {(const float*)d_in[3], (const float*)d_in[11]};
  const float* conv_w[2] = {(const float*)d_in[4], (const float*)d_in[12]};
  const float* conv_b[2] = {(const float*)d_in[5], (const float*)d_in[13]};
  const float* dt_bias[2] = {(const float*)d_in[6], (const float*)d_in[14]};
  const float* A_log[2] = {(const float*)d_in[7], (const float*)d_in[15]};
  const float* Dp[2] = {(const float*)d_in[8], (const float*)d_in[16]};
  const float* norm_w[2] = {(const float*)d_in[9], (const float*)d_in[17]};
  const float* out_w[2] = {(const float*)d_in[10], (const float*)d_in[18]};
  (void)in_sizes; (void)n_in;

  char* ws = (char*)d_ws;
  size_t off = 0;
  auto alloc = [&](size_t bytes) {
    size_t o = off;
    off = (off + bytes + 255) & ~(size_t)255;
    return o;
  };
  bf16* x_bf  = (bf16*)(ws + alloc((size_t)NTOK * DMODEL * 2));          // 25.2 MB
  bf16* w_in  = (bf16*)(ws + alloc((size_t)NROWS_XBC * DMODEL * 2));     //  4.9 MB
  bf16* wf1   = (bf16*)(ws + alloc((size_t)DMODEL * DMODEL * 2));        //  1.2 MB
  bf16* owT   = (bf16*)(ws + alloc((size_t)DINNER * DMODEL * 2));        //  2.4 MB
  bf16* wc    = (bf16*)(ws + alloc((size_t)DMODEL * DINNER * 2));        //  2.4 MB
  bf16* xbcr  = (bf16*)(ws + alloc((size_t)NTOK * CONVDIM * 2));         // 54.5 MB (ynorm aliases)
  float* dtb  = (float*)(ws + alloc((size_t)NTOK * HN * 4));             //  1.6 MB
  float* dlb  = (float*)(ws + alloc((size_t)NTOK * HN * 4));             //  1.6 MB
  float* laq  = (float*)(ws + alloc((size_t)BATCHN * HN * NCHUNK * 4));  //  0.02 MB
  bf16* Bblob = (bf16*)(ws + alloc((size_t)NTOK * DSTATE * 2));          //  2.1 MB
  bf16* Cblob = (bf16*)(ws + alloc((size_t)NTOK * DSTATE * 2));          //  2.1 MB
  bf16* Gblob = (bf16*)(ws + alloc((size_t)NTOK * DINNER * 2));          // 50.3 MB (z aliases)
  bf16* Yblob = (bf16*)(ws + alloc((size_t)NTOK * DINNER * 2));          // 50.3 MB
  bf16* zbuf  = Gblob;  // z GEMM output reuses G/prefix blob (dead after chunk_inter)
  bf16* ynorm = xbcr;   // normalized y reuses xbcr (dead after chunk_inter)

  if (ws_size < off) {  // diagnostic: clean absmax(=max|ref|) failure, not a crash
    hipMemsetAsync(d_out, 0, (size_t)out_size * 4, stream);
    return;
  }

  cast_x_kernel<<<(NTOK * DMODEL) / 256, 256, 0, stream>>>(x, x_bf);

  for (int dir = 0; dir < 2; dir++) {
    cast_kernel<<<(NROWS_XBC * DMODEL) / 256, 256, 0, stream>>>(in_w[dir], w_in);
    // in-proj xBC part (in_w rows 1536..3200) -> xbcr
    gemm_lds<true><<<dim3(NTOK / 128, CONVDIM / 128), 256, 0, stream>>>(
        x_bf, w_in + (size_t)DINNER * DMODEL, xbcr, DMODEL, CONVDIM, dir, 0, 0, nullptr);
    // exact fp32 dt + log-decay
    dt_kernel<<<NTOK, 256, 0, stream>>>(x, in_w[dir], dt_bias[dir], A_log[dir], dtb, dlb, dir);
    // B/C conv+silu once -> per-chunk blobs
    conv_bc_kernel<<<(NTOK * 128) / 256, 256, 0, stream>>>(
        xbcr, conv_w[dir], conv_b[dir], Bblob, Cblob);
    // chunked SSD
    chunk_intra_kernel<<<BATCHN * HN * NCHUNK, 256, 0, stream>>>(
        xbcr, Bblob, Cblob, conv_w[dir], conv_b[dir], dtb, dlb, Dp[dir], Yblob, Gblob, laq);
    state_scan_kernel<<<BATCHN * HN, 256, 0, stream>>>(Gblob, laq);
    chunk_inter_kernel<<<BATCHN * HN * NCHUNK, 256, 0, stream>>>(Cblob, dlb, Gblob, Yblob);
    // in-proj z part (in_w rows 0..1536) -> zbuf (blob region, now dead)
    gemm_lds<true><<<dim3(NTOK / 128, DINNER / 128), 256, 0, stream>>>(
        x_bf, w_in, zbuf, DMODEL, DINNER, dir, 0, 0, nullptr);
    // gated RMSNorm -> ynorm rows (xbcr region, now dead)
    norm_kernel<<<NTOK, 256, 0, stream>>>(Yblob, zbuf, norm_w[dir], ynorm);
    // combined weight wc = fus_half @ out_w  (768x1536)
    cast_strided_kernel<<<(DMODEL * DMODEL) / 256, 256, 0, stream>>>(
        fus_w + dir * DMODEL, wf1, DMODEL, 2 * DMODEL);
    transpose_ow_kernel<<<(DINNER * DMODEL) / 256, 256, 0, stream>>>(out_w[dir], owT);
    gemm_lds<true><<<dim3(DMODEL / 128, DINNER / 128), 256, 0, stream>>>(
        wf1, owT, wc, DMODEL, DINNER, 0, 0, 0, nullptr);
    // out-proj + fusion: d_out (+)= ynorm @ wc^T (dir1 un-flips rows, accumulates)
    gemm_lds<false><<<dim3(NTOK / 128, DMODEL / 128), 256, 0, stream>>>(
        ynorm, wc, d_out, DINNER, DMODEL, 0, dir, dir, dir == 0 ? fus_b : nullptr);
  }
}